// Round 1
// baseline (1189.976 us; speedup 1.0000x reference)
//
#include <hip/hip_runtime.h>
#include <hip/hip_bf16.h>

// Problem geometry (fixed)
#define BDIM 4
#define CDIM 256
#define HDIM 64
#define WDIM 64
#define LDIM 4096   // H*W
#define ROWS 16384  // B*L

// ---------------------------------------------------------------------------
// LayerNorm over C=256. One wave (64 lanes) per row; 4 rows per block.
// transposed_in=1: input is (B,C,H,W), also writes raw transposed copy to xT.
// transposed_in=0: input is (ROWS,256) contiguous.
// ---------------------------------------------------------------------------
__global__ __launch_bounds__(256) void norm_kernel(
    const float* __restrict__ xin,
    const float* __restrict__ w, const float* __restrict__ b,
    float* __restrict__ out,
    float* __restrict__ xT,
    int transposed_in)
{
    int wave = threadIdx.x >> 6;
    int lane = threadIdx.x & 63;
    int row = blockIdx.x * 4 + wave;
    float v[4];
    float sum = 0.f, sumsq = 0.f;
    if (transposed_in) {
        int bb = row >> 12;
        int l = row & 4095;
        const float* xb = xin + (size_t)bb * (CDIM * LDIM) + l;
        #pragma unroll
        for (int i = 0; i < 4; ++i) {
            int c = lane + i * 64;
            float t = xb[(size_t)c * LDIM];
            v[i] = t; sum += t; sumsq += t * t;
        }
    } else {
        const float* xr = xin + (size_t)row * CDIM;
        #pragma unroll
        for (int i = 0; i < 4; ++i) {
            float t = xr[lane + i * 64];
            v[i] = t; sum += t; sumsq += t * t;
        }
    }
    #pragma unroll
    for (int off = 32; off > 0; off >>= 1) {
        sum   += __shfl_xor(sum, off);
        sumsq += __shfl_xor(sumsq, off);
    }
    float mean = sum * (1.f / 256.f);
    float var  = sumsq * (1.f / 256.f) - mean * mean;
    float inv  = rsqrtf(var + 1e-5f);
    float* orow = out + (size_t)row * CDIM;
    #pragma unroll
    for (int i = 0; i < 4; ++i) {
        int c = lane + i * 64;
        if (xT) xT[(size_t)row * CDIM + c] = v[i];
        orow[c] = (v[i] - mean) * inv * w[c] + b[c];
    }
}

// ---------------------------------------------------------------------------
// fp32 tiled GEMM: out[m,n] = sum_k A[m,k]*Wm[n,k]  (+bias, +gelu, +resid)
// A: Mx K row-major, Wm: N x K row-major (i.e. computes A @ Wm^T).
// 64x64 block tile, KT=16, 256 threads, 4x4 per thread.
// mode: 0 plain, 2 bias+gelu(exact), 3 bias+resid
// ---------------------------------------------------------------------------
__global__ __launch_bounds__(256) void gemm_kernel(
    const float* __restrict__ A,
    const float* __restrict__ Wm,
    const float* __restrict__ bias,
    const float* __restrict__ resid,
    float* __restrict__ out,
    int N, int K, int mode)
{
    __shared__ float As[16][65];   // [k][m]
    __shared__ float Bs[16][65];   // [k][n]
    int tid = threadIdx.x;
    int tx = tid & 15, ty = tid >> 4;
    int n0 = blockIdx.x * 64, m0 = blockIdx.y * 64;
    float acc[4][4] = {{0.f}};
    int r  = tid >> 2;   // 0..63
    int c4 = tid & 3;    // 0..3
    for (int k0 = 0; k0 < K; k0 += 16) {
        float4 a4 = *reinterpret_cast<const float4*>(&A [(size_t)(m0 + r) * K + k0 + c4 * 4]);
        float4 b4 = *reinterpret_cast<const float4*>(&Wm[(size_t)(n0 + r) * K + k0 + c4 * 4]);
        As[c4 * 4 + 0][r] = a4.x; As[c4 * 4 + 1][r] = a4.y;
        As[c4 * 4 + 2][r] = a4.z; As[c4 * 4 + 3][r] = a4.w;
        Bs[c4 * 4 + 0][r] = b4.x; Bs[c4 * 4 + 1][r] = b4.y;
        Bs[c4 * 4 + 2][r] = b4.z; Bs[c4 * 4 + 3][r] = b4.w;
        __syncthreads();
        #pragma unroll
        for (int kk = 0; kk < 16; ++kk) {
            float a[4], bb[4];
            #pragma unroll
            for (int i = 0; i < 4; ++i) a[i]  = As[kk][ty * 4 + i];
            #pragma unroll
            for (int j = 0; j < 4; ++j) bb[j] = Bs[kk][tx * 4 + j];
            #pragma unroll
            for (int i = 0; i < 4; ++i)
                #pragma unroll
                for (int j = 0; j < 4; ++j)
                    acc[i][j] += a[i] * bb[j];
        }
        __syncthreads();
    }
    #pragma unroll
    for (int i = 0; i < 4; ++i) {
        int m = m0 + ty * 4 + i;
        #pragma unroll
        for (int j = 0; j < 4; ++j) {
            int n = n0 + tx * 4 + j;
            float v = acc[i][j];
            if (mode >= 2) v += bias[n];
            if (mode == 2) v = 0.5f * v * (1.f + erff(v * 0.70710678118654752f));
            if (mode == 3) v += resid[(size_t)m * N + n];
            out[(size_t)m * N + n] = v;
        }
    }
}

// ---------------------------------------------------------------------------
// Fused windowed attention + LePE for both branches.
// grid = 256 blocks: pid = br*128 + win*4 + head
//   br0: windows 64x8  (nH=1,nW=8): l = hs*64 + wi*8 + ws, kk = hs*8+ws
//   br1: windows 8x64  (nH=8,nW=1): l = wi*512 + kk,       kk = hs*64+ws
// K(=Q) and V tiles (512x32 fp32) staged in LDS, stride 36 to avoid bank
// conflicts on per-lane-row reads. Online softmax, hd=32 accumulators.
// LePE depthwise 3x3 (SAME, per-window zero pad) computed from the V tile.
// ---------------------------------------------------------------------------
__global__ __launch_bounds__(256) void attn_kernel(
    const float* __restrict__ qkv,   // ROWS x 512
    const float* __restrict__ gw0, const float* __restrict__ gb0,
    const float* __restrict__ gw1, const float* __restrict__ gb1,
    float* __restrict__ att)         // ROWS x 256
{
    __shared__ float ks[512][36];
    __shared__ float vs[512][36];
    int pid  = blockIdx.x;
    int br   = pid >> 7;
    int head = pid & 3;
    int win  = (pid >> 2) & 31;
    int bb   = win >> 3;
    int wi   = win & 7;
    int tid  = threadIdx.x;
    int qk_off = br * 128 + head * 32;
    int v_off  = 256 + qk_off;

    for (int it = 0; it < 16; ++it) {
        int kk = it * 32 + (tid >> 3);
        int q4 = tid & 7;
        int l  = (br == 0) ? (((kk >> 3) * 64) + wi * 8 + (kk & 7))
                           : (wi * 512 + kk);
        size_t base = ((size_t)(bb * 4096 + l)) * 512;
        float4 kv = *reinterpret_cast<const float4*>(&qkv[base + qk_off + q4 * 4]);
        float4 vv = *reinterpret_cast<const float4*>(&qkv[base + v_off  + q4 * 4]);
        *reinterpret_cast<float4*>(&ks[kk][q4 * 4]) = kv;
        *reinterpret_cast<float4*>(&vs[kk][q4 * 4]) = vv;
    }
    __syncthreads();

    const float scale = 0.17677669529663689f;  // 32^-0.5
    const float* gw = br ? gw1 : gb0;  // placeholder fixed below
    gw = br ? gw1 : gw0;
    const float* gb = br ? gb1 : gb0;
    int Wsp = (br == 0) ? 8 : 64;
    int Hsp = (br == 0) ? 64 : 8;

    for (int rr = 0; rr < 2; ++rr) {
        int q = rr * 256 + tid;
        float qreg[32];
        #pragma unroll
        for (int d = 0; d < 32; ++d) qreg[d] = ks[q][d] * scale;
        float m = -1e30f, s = 0.f;
        float acc[32];
        #pragma unroll
        for (int d = 0; d < 32; ++d) acc[d] = 0.f;
        for (int kk = 0; kk < 512; ++kk) {
            float dot = 0.f;
            #pragma unroll
            for (int d = 0; d < 32; ++d) dot += qreg[d] * ks[kk][d];
            float nm = fmaxf(m, dot);
            float f  = __expf(m - nm);
            float p  = __expf(dot - nm);
            s = s * f + p;
            #pragma unroll
            for (int d = 0; d < 32; ++d) acc[d] = acc[d] * f + p * vs[kk][d];
            m = nm;
        }
        float inv = 1.f / s;

        int hs = (br == 0) ? (q >> 3) : (q >> 6);
        int ws = (br == 0) ? (q & 7)  : (q & 63);
        int l  = (br == 0) ? (hs * 64 + wi * 8 + ws) : (wi * 512 + q);
        float outv[32];
        #pragma unroll
        for (int d = 0; d < 32; ++d) {
            int ch = head * 32 + d;
            float lep = gb[ch];
            #pragma unroll
            for (int dy = -1; dy <= 1; ++dy) {
                int hh = hs + dy;
                if (hh < 0 || hh >= Hsp) continue;
                #pragma unroll
                for (int dx = -1; dx <= 1; ++dx) {
                    int ww = ws + dx;
                    if (ww < 0 || ww >= Wsp) continue;
                    lep += vs[hh * Wsp + ww][d] * gw[ch * 9 + (dy + 1) * 3 + (dx + 1)];
                }
            }
            outv[d] = acc[d] * inv + lep;
        }
        float* orow = att + ((size_t)(bb * 4096 + l)) * 256 + br * 128 + head * 32;
        #pragma unroll
        for (int i = 0; i < 8; ++i) {
            *reinterpret_cast<float4*>(&orow[i * 4]) =
                make_float4(outv[i*4], outv[i*4+1], outv[i*4+2], outv[i*4+3]);
        }
    }
}

// ---------------------------------------------------------------------------
extern "C" void kernel_launch(void* const* d_in, const int* in_sizes, int n_in,
                              void* d_out, int out_size, void* d_ws, size_t ws_size,
                              hipStream_t stream) {
    const float* x     = (const float*)d_in[0];
    const float* n1w   = (const float*)d_in[1];
    const float* n1b   = (const float*)d_in[2];
    const float* qkvw  = (const float*)d_in[3];
    const float* gw0   = (const float*)d_in[4];
    const float* gb0   = (const float*)d_in[5];
    const float* gw1   = (const float*)d_in[6];
    const float* gb1   = (const float*)d_in[7];
    const float* projw = (const float*)d_in[8];
    const float* projb = (const float*)d_in[9];
    const float* n2w   = (const float*)d_in[10];
    const float* n2b   = (const float*)d_in[11];
    const float* fc1w  = (const float*)d_in[12];
    const float* fc1b  = (const float*)d_in[13];
    const float* fc2w  = (const float*)d_in[14];
    const float* fc2b  = (const float*)d_in[15];
    float* out = (float*)d_out;
    float* ws  = (float*)d_ws;

    float* xT   = ws;                    // 16384*256
    float* img  = ws + 4194304;          // 16384*256
    float* qkv  = ws + 8388608;          // 16384*512
    float* att  = ws + 16777216;         // 16384*256
    float* ynorm = img;                  // reuse (img dead after qkv GEMM)
    float* hbuf  = qkv;                  // reuse (qkv dead after attention)

    // norm1 (+ raw transpose for residual)
    norm_kernel<<<4096, 256, 0, stream>>>(x, n1w, n1b, img, xT, 1);
    // qkv = img @ qkv_w^T   (16384 x 512)
    gemm_kernel<<<dim3(8, 256), 256, 0, stream>>>(img, qkvw, nullptr, nullptr, qkv, 512, 256, 0);
    // windowed attention + LePE, both branches -> att (16384 x 256)
    attn_kernel<<<256, 256, 0, stream>>>(qkv, gw0, gb0, gw1, gb1, att);
    // x = xT + att @ proj_w^T + proj_b  -> d_out
    gemm_kernel<<<dim3(4, 256), 256, 0, stream>>>(att, projw, projb, xT, out, 256, 256, 3);
    // norm2
    norm_kernel<<<4096, 256, 0, stream>>>(out, n2w, n2b, ynorm, nullptr, 0);
    // MLP, row-chunked so hidden buffer (8192x1024) fits the qkv buffer
    for (int ch = 0; ch < 2; ++ch) {
        const float* Ain = ynorm + (size_t)ch * 8192 * 256;
        float* outc = out + (size_t)ch * 8192 * 256;
        gemm_kernel<<<dim3(16, 128), 256, 0, stream>>>(Ain, fc1w, fc1b, nullptr, hbuf, 1024, 256, 2);
        gemm_kernel<<<dim3(4, 128), 256, 0, stream>>>(hbuf, fc2w, fc2b, outc, outc, 256, 1024, 3);
    }
}

// Round 3
// 777.532 us; speedup vs baseline: 1.5305x; 1.5305x over previous
//
#include <hip/hip_runtime.h>
#include <hip/hip_bf16.h>

// Problem geometry (fixed)
#define BDIM 4
#define CDIM 256
#define HDIM 64
#define WDIM 64
#define LDIM 4096   // H*W
#define ROWS 16384  // B*L

// ---------------------------------------------------------------------------
// LayerNorm over C=256. One wave (64 lanes) per row; 4 rows per block.
// ---------------------------------------------------------------------------
__global__ __launch_bounds__(256) void norm_kernel(
    const float* __restrict__ xin,
    const float* __restrict__ w, const float* __restrict__ b,
    float* __restrict__ out,
    float* __restrict__ xT,
    int transposed_in)
{
    int wave = threadIdx.x >> 6;
    int lane = threadIdx.x & 63;
    int row = blockIdx.x * 4 + wave;
    float v[4];
    float sum = 0.f, sumsq = 0.f;
    if (transposed_in) {
        int bb = row >> 12;
        int l = row & 4095;
        const float* xb = xin + (size_t)bb * (CDIM * LDIM) + l;
        #pragma unroll
        for (int i = 0; i < 4; ++i) {
            int c = lane + i * 64;
            float t = xb[(size_t)c * LDIM];
            v[i] = t; sum += t; sumsq += t * t;
        }
    } else {
        const float* xr = xin + (size_t)row * CDIM;
        #pragma unroll
        for (int i = 0; i < 4; ++i) {
            float t = xr[lane + i * 64];
            v[i] = t; sum += t; sumsq += t * t;
        }
    }
    #pragma unroll
    for (int off = 32; off > 0; off >>= 1) {
        sum   += __shfl_xor(sum, off);
        sumsq += __shfl_xor(sumsq, off);
    }
    float mean = sum * (1.f / 256.f);
    float var  = sumsq * (1.f / 256.f) - mean * mean;
    float inv  = rsqrtf(var + 1e-5f);
    float* orow = out + (size_t)row * CDIM;
    #pragma unroll
    for (int i = 0; i < 4; ++i) {
        int c = lane + i * 64;
        if (xT) xT[(size_t)row * CDIM + c] = v[i];
        orow[c] = (v[i] - mean) * inv * w[c] + b[c];
    }
}

// ---------------------------------------------------------------------------
// fp32 tiled GEMM: out = A @ Wm^T (+bias/+gelu/+resid). 64x64 tile, KT=16.
// mode: 0 plain, 2 bias+gelu(exact), 3 bias+resid
// ---------------------------------------------------------------------------
__global__ __launch_bounds__(256) void gemm_kernel(
    const float* __restrict__ A,
    const float* __restrict__ Wm,
    const float* __restrict__ bias,
    const float* __restrict__ resid,
    float* __restrict__ out,
    int N, int K, int mode)
{
    __shared__ float As[16][65];   // [k][m]
    __shared__ float Bs[16][65];   // [k][n]
    int tid = threadIdx.x;
    int tx = tid & 15, ty = tid >> 4;
    int n0 = blockIdx.x * 64, m0 = blockIdx.y * 64;
    float acc[4][4] = {{0.f}};
    int r  = tid >> 2;   // 0..63
    int c4 = tid & 3;    // 0..3
    for (int k0 = 0; k0 < K; k0 += 16) {
        float4 a4 = *reinterpret_cast<const float4*>(&A [(size_t)(m0 + r) * K + k0 + c4 * 4]);
        float4 b4 = *reinterpret_cast<const float4*>(&Wm[(size_t)(n0 + r) * K + k0 + c4 * 4]);
        As[c4 * 4 + 0][r] = a4.x; As[c4 * 4 + 1][r] = a4.y;
        As[c4 * 4 + 2][r] = a4.z; As[c4 * 4 + 3][r] = a4.w;
        Bs[c4 * 4 + 0][r] = b4.x; Bs[c4 * 4 + 1][r] = b4.y;
        Bs[c4 * 4 + 2][r] = b4.z; Bs[c4 * 4 + 3][r] = b4.w;
        __syncthreads();
        #pragma unroll
        for (int kk = 0; kk < 16; ++kk) {
            float a[4], bb[4];
            #pragma unroll
            for (int i = 0; i < 4; ++i) a[i]  = As[kk][ty * 4 + i];
            #pragma unroll
            for (int j = 0; j < 4; ++j) bb[j] = Bs[kk][tx * 4 + j];
            #pragma unroll
            for (int i = 0; i < 4; ++i)
                #pragma unroll
                for (int j = 0; j < 4; ++j)
                    acc[i][j] += a[i] * bb[j];
        }
        __syncthreads();
    }
    #pragma unroll
    for (int i = 0; i < 4; ++i) {
        int m = m0 + ty * 4 + i;
        #pragma unroll
        for (int j = 0; j < 4; ++j) {
            int n = n0 + tx * 4 + j;
            float v = acc[i][j];
            if (mode >= 2) v += bias[n];
            if (mode == 2) v = 0.5f * v * (1.f + erff(v * 0.70710678118654752f));
            if (mode == 3) v += resid[(size_t)m * N + n];
            out[(size_t)m * N + n] = v;
        }
    }
}

// ---------------------------------------------------------------------------
// Fused windowed attention + LePE, occupancy-optimized.
// grid = 1024 blocks of 128 threads: pid = wh*4 + qt
//   wh = br*128 + win*4 + head; qt = q-tile (128 rows of the 512-row window)
// K/V staged in 128-row LDS chunks (32 KB total). Each thread owns one q row;
// batch-4 online softmax; inner LDS reads are wave-uniform broadcasts.
// LePE 3x3 depthwise (per-window zero pad) read from global (L2-hot).
// ---------------------------------------------------------------------------
__global__ __launch_bounds__(128) void attn_kernel(
    const float* __restrict__ qkv,   // ROWS x 512
    const float* __restrict__ gw0, const float* __restrict__ gb0,
    const float* __restrict__ gw1, const float* __restrict__ gb1,
    float* __restrict__ att)         // ROWS x 256
{
    __shared__ float ks[128][32];
    __shared__ float vs[128][32];
    int pid  = blockIdx.x;
    int qt   = pid & 3;
    int wh   = pid >> 2;
    int br   = wh >> 7;
    int head = wh & 3;
    int win  = (wh >> 2) & 31;
    int bb   = win >> 3;
    int wi   = win & 7;
    int tid  = threadIdx.x;
    int qk_off = br * 128 + head * 32;
    int v_off  = 256 + qk_off;
    const float scale = 0.17677669529663689f;  // 32^-0.5

    // this thread's q row
    int q   = qt * 128 + tid;
    int l_q = (br == 0) ? ((q >> 3) * 64 + wi * 8 + (q & 7)) : (wi * 512 + q);
    const float* qrow = qkv + ((size_t)(bb * 4096 + l_q)) * 512 + qk_off;
    float qreg[32];
    #pragma unroll
    for (int i = 0; i < 8; ++i) {
        float4 t = *reinterpret_cast<const float4*>(&qrow[i * 4]);
        qreg[i*4+0] = t.x * scale; qreg[i*4+1] = t.y * scale;
        qreg[i*4+2] = t.z * scale; qreg[i*4+3] = t.w * scale;
    }

    float m = -1e30f, s = 0.f;
    float acc[32];
    #pragma unroll
    for (int d = 0; d < 32; ++d) acc[d] = 0.f;

    for (int c = 0; c < 4; ++c) {
        // cooperative load of 128-row K/V chunk: 128 rows x 8 float4 = 1024 each
        #pragma unroll
        for (int i = 0; i < 8; ++i) {
            int idx = i * 128 + tid;     // 0..1023
            int row = idx >> 3, q4 = idx & 7;
            int kk  = c * 128 + row;
            int l   = (br == 0) ? ((kk >> 3) * 64 + wi * 8 + (kk & 7)) : (wi * 512 + kk);
            size_t base = ((size_t)(bb * 4096 + l)) * 512;
            *reinterpret_cast<float4*>(&ks[row][q4 * 4]) =
                *reinterpret_cast<const float4*>(&qkv[base + qk_off + q4 * 4]);
            *reinterpret_cast<float4*>(&vs[row][q4 * 4]) =
                *reinterpret_cast<const float4*>(&qkv[base + v_off + q4 * 4]);
        }
        __syncthreads();

        for (int kk = 0; kk < 128; kk += 4) {
            float d0 = 0.f, d1 = 0.f, d2 = 0.f, d3 = 0.f;
            #pragma unroll
            for (int d = 0; d < 32; ++d) {
                float qd = qreg[d];
                d0 += qd * ks[kk + 0][d];
                d1 += qd * ks[kk + 1][d];
                d2 += qd * ks[kk + 2][d];
                d3 += qd * ks[kk + 3][d];
            }
            float m4 = fmaxf(fmaxf(d0, d1), fmaxf(d2, d3));
            float nm = fmaxf(m, m4);
            float f  = __expf(m - nm);
            float p0 = __expf(d0 - nm), p1 = __expf(d1 - nm);
            float p2 = __expf(d2 - nm), p3 = __expf(d3 - nm);
            s = s * f + (p0 + p1) + (p2 + p3);
            #pragma unroll
            for (int d = 0; d < 32; ++d) {
                float a = acc[d] * f;
                a += p0 * vs[kk + 0][d];
                a += p1 * vs[kk + 1][d];
                a += p2 * vs[kk + 2][d];
                a += p3 * vs[kk + 3][d];
                acc[d] = a;
            }
            m = nm;
        }
        __syncthreads();
    }

    // epilogue: normalize + LePE (3x3 depthwise, per-window zero pad)
    float inv = 1.f / s;
    int Hsp = (br == 0) ? 64 : 8;
    int Wsp = (br == 0) ? 8 : 64;
    int hs  = (br == 0) ? (q >> 3) : (q >> 6);
    int wsx = (br == 0) ? (q & 7)  : (q & 63);
    const float* gw = br ? gw1 : gw0;
    const float* gb = br ? gb1 : gb0;
    #pragma unroll
    for (int d = 0; d < 32; ++d) acc[d] = acc[d] * inv + gb[head * 32 + d];

    #pragma unroll
    for (int dy = -1; dy <= 1; ++dy) {
        int hh = hs + dy;
        if (hh < 0 || hh >= Hsp) continue;
        #pragma unroll
        for (int dx = -1; dx <= 1; ++dx) {
            int ww = wsx + dx;
            if (ww < 0 || ww >= Wsp) continue;
            int l_n = (br == 0) ? (hh * 64 + wi * 8 + ww) : (wi * 512 + hh * 64 + ww);
            const float* vrow = qkv + ((size_t)(bb * 4096 + l_n)) * 512 + v_off;
            int t = (dy + 1) * 3 + (dx + 1);
            #pragma unroll
            for (int i = 0; i < 8; ++i) {
                float4 vv = *reinterpret_cast<const float4*>(&vrow[i * 4]);
                acc[i*4+0] += vv.x * gw[(head * 32 + i*4 + 0) * 9 + t];
                acc[i*4+1] += vv.y * gw[(head * 32 + i*4 + 1) * 9 + t];
                acc[i*4+2] += vv.z * gw[(head * 32 + i*4 + 2) * 9 + t];
                acc[i*4+3] += vv.w * gw[(head * 32 + i*4 + 3) * 9 + t];
            }
        }
    }

    float* orow = att + ((size_t)(bb * 4096 + l_q)) * 256 + br * 128 + head * 32;
    #pragma unroll
    for (int i = 0; i < 8; ++i) {
        *reinterpret_cast<float4*>(&orow[i * 4]) =
            make_float4(acc[i*4], acc[i*4+1], acc[i*4+2], acc[i*4+3]);
    }
}

// ---------------------------------------------------------------------------
extern "C" void kernel_launch(void* const* d_in, const int* in_sizes, int n_in,
                              void* d_out, int out_size, void* d_ws, size_t ws_size,
                              hipStream_t stream) {
    const float* x     = (const float*)d_in[0];
    const float* n1w   = (const float*)d_in[1];
    const float* n1b   = (const float*)d_in[2];
    const float* qkvw  = (const float*)d_in[3];
    const float* gw0   = (const float*)d_in[4];
    const float* gb0   = (const float*)d_in[5];
    const float* gw1   = (const float*)d_in[6];
    const float* gb1   = (const float*)d_in[7];
    const float* projw = (const float*)d_in[8];
    const float* projb = (const float*)d_in[9];
    const float* n2w   = (const float*)d_in[10];
    const float* n2b   = (const float*)d_in[11];
    const float* fc1w  = (const float*)d_in[12];
    const float* fc1b  = (const float*)d_in[13];
    const float* fc2w  = (const float*)d_in[14];
    const float* fc2b  = (const float*)d_in[15];
    float* out = (float*)d_out;
    float* ws  = (float*)d_ws;

    float* xT   = ws;                    // 16384*256
    float* img  = ws + 4194304;          // 16384*256
    float* qkv  = ws + 8388608;          // 16384*512
    float* att  = ws + 16777216;         // 16384*256
    float* ynorm = img;                  // reuse (img dead after qkv GEMM)
    float* hbuf  = qkv;                  // reuse (qkv dead after attention)

    // norm1 (+ raw transpose for residual)
    norm_kernel<<<4096, 256, 0, stream>>>(x, n1w, n1b, img, xT, 1);
    // qkv = img @ qkv_w^T   (16384 x 512)
    gemm_kernel<<<dim3(8, 256), 256, 0, stream>>>(img, qkvw, nullptr, nullptr, qkv, 512, 256, 0);
    // windowed attention + LePE, both branches -> att (16384 x 256)
    attn_kernel<<<1024, 128, 0, stream>>>(qkv, gw0, gb0, gw1, gb1, att);
    // x = xT + att @ proj_w^T + proj_b  -> d_out
    gemm_kernel<<<dim3(4, 256), 256, 0, stream>>>(att, projw, projb, xT, out, 256, 256, 3);
    // norm2
    norm_kernel<<<4096, 256, 0, stream>>>(out, n2w, n2b, ynorm, nullptr, 0);
    // MLP, row-chunked so hidden buffer (8192x1024) fits the qkv buffer
    for (int ch = 0; ch < 2; ++ch) {
        const float* Ain = ynorm + (size_t)ch * 8192 * 256;
        float* outc = out + (size_t)ch * 8192 * 256;
        gemm_kernel<<<dim3(16, 128), 256, 0, stream>>>(Ain, fc1w, fc1b, nullptr, hbuf, 1024, 256, 2);
        gemm_kernel<<<dim3(4, 128), 256, 0, stream>>>(hbuf, fc2w, fc2b, outc, outc, 256, 1024, 3);
    }
}

// Round 4
// 382.148 us; speedup vs baseline: 3.1139x; 2.0346x over previous
//
#include <hip/hip_runtime.h>
#include <hip/hip_bf16.h>

// Problem geometry (fixed)
#define BDIM 4
#define CDIM 256
#define HDIM 64
#define WDIM 64
#define LDIM 4096   // H*W
#define ROWS 16384  // B*L

typedef __attribute__((ext_vector_type(8))) short short8;
typedef __attribute__((ext_vector_type(4))) float f32x4;

static __device__ __forceinline__ unsigned short f2bf(float f) {
    unsigned int x = __float_as_uint(f);
    unsigned int r = (x + 0x7fffu + ((x >> 16) & 1u)) >> 16;   // RNE
    return (unsigned short)r;
}

// ---------------------------------------------------------------------------
// fp32 -> bf16 conversion (weights), float4-vectorized, n4 = n/4
// ---------------------------------------------------------------------------
__global__ __launch_bounds__(256) void cvt_kernel(
    const float* __restrict__ in, unsigned short* __restrict__ out, int n4)
{
    int i = blockIdx.x * 256 + threadIdx.x;
    if (i >= n4) return;
    float4 f = reinterpret_cast<const float4*>(in)[i];
    unsigned int w0 = (unsigned int)f2bf(f.x) | ((unsigned int)f2bf(f.y) << 16);
    unsigned int w1 = (unsigned int)f2bf(f.z) | ((unsigned int)f2bf(f.w) << 16);
    reinterpret_cast<uint2*>(out)[i] = make_uint2(w0, w1);
}

// ---------------------------------------------------------------------------
// LayerNorm over C=256 -> bf16 out (+ optional raw fp32 transpose copy xT).
// One wave per row; 4 rows per block.
// ---------------------------------------------------------------------------
__global__ __launch_bounds__(256) void norm_kernel(
    const float* __restrict__ xin,
    const float* __restrict__ w, const float* __restrict__ b,
    unsigned short* __restrict__ out,
    float* __restrict__ xT,
    int transposed_in)
{
    int wave = threadIdx.x >> 6;
    int lane = threadIdx.x & 63;
    int row = blockIdx.x * 4 + wave;
    float v[4];
    float sum = 0.f, sumsq = 0.f;
    if (transposed_in) {
        int bb = row >> 12;
        int l = row & 4095;
        const float* xb = xin + (size_t)bb * (CDIM * LDIM) + l;
        #pragma unroll
        for (int i = 0; i < 4; ++i) {
            int c = lane + i * 64;
            float t = xb[(size_t)c * LDIM];
            v[i] = t; sum += t; sumsq += t * t;
        }
    } else {
        const float* xr = xin + (size_t)row * CDIM;
        #pragma unroll
        for (int i = 0; i < 4; ++i) {
            float t = xr[lane + i * 64];
            v[i] = t; sum += t; sumsq += t * t;
        }
    }
    #pragma unroll
    for (int off = 32; off > 0; off >>= 1) {
        sum   += __shfl_xor(sum, off);
        sumsq += __shfl_xor(sumsq, off);
    }
    float mean = sum * (1.f / 256.f);
    float var  = sumsq * (1.f / 256.f) - mean * mean;
    float inv  = rsqrtf(var + 1e-5f);
    unsigned short* orow = out + (size_t)row * CDIM;
    #pragma unroll
    for (int i = 0; i < 4; ++i) {
        int c = lane + i * 64;
        if (xT) xT[(size_t)row * CDIM + c] = v[i];
        orow[c] = f2bf((v[i] - mean) * inv * w[c] + b[c]);
    }
}

// ---------------------------------------------------------------------------
// bf16 MFMA GEMM: C = A @ B^T (+ bias / gelu / resid), fp32 accumulate.
// A: M x K bf16 row-major, Bm: N x K bf16 row-major.
// 128x128 tile, BK=32, 256 threads = 4 waves (2x2), 4x4 16x16x32 frags/wave.
// Staging via global_load_lds(16B); XOR swizzle (colblk ^= row&3) applied to
// the GLOBAL source (linear LDS dest) and to the ds_read - rule both-sides.
// mode: 0 = plain -> f32; 2 = +bias, gelu -> bf16; 3 = +bias +resid -> f32
// ---------------------------------------------------------------------------
__global__ __launch_bounds__(256) void mfma_gemm(
    const unsigned short* __restrict__ A,
    const unsigned short* __restrict__ Bm,
    const float* __restrict__ bias,
    const float* __restrict__ resid,
    void* __restrict__ outp,
    int N, int K, int mode)
{
    __shared__ unsigned short As[128 * 32];
    __shared__ unsigned short Bs[128 * 32];
    int tid  = threadIdx.x;
    int lane = tid & 63;
    int w    = tid >> 6;
    int wr   = w >> 1, wc = w & 1;
    int l15  = lane & 15, kbl = lane >> 4;
    int n0 = blockIdx.x * 128, m0 = blockIdx.y * 128;

    f32x4 acc[4][4];
    #pragma unroll
    for (int m = 0; m < 4; ++m)
        #pragma unroll
        for (int n = 0; n < 4; ++n)
            acc[m][n] = (f32x4){0.f, 0.f, 0.f, 0.f};

    int kbr = kbl ^ (l15 & 3);   // swizzled k-block for fragment reads

    for (int k0 = 0; k0 < K; k0 += 32) {
        // stage A,B tiles: 512 chunks of 16B each, 2 per thread per buffer
        #pragma unroll
        for (int i = 0; i < 2; ++i) {
            int c = i * 256 + tid;          // 0..511
            int row = c >> 2, kbp = c & 3;
            int cbg = kbp ^ (row & 3);      // pre-swizzled global colblk
            const unsigned short* ga = A  + (size_t)(m0 + row) * K + k0 + cbg * 8;
            const unsigned short* gb = Bm + (size_t)(n0 + row) * K + k0 + cbg * 8;
            __builtin_amdgcn_global_load_lds(
                (const __attribute__((address_space(1))) void*)ga,
                (__attribute__((address_space(3))) void*)(As + c * 8), 16, 0, 0);
            __builtin_amdgcn_global_load_lds(
                (const __attribute__((address_space(1))) void*)gb,
                (__attribute__((address_space(3))) void*)(Bs + c * 8), 16, 0, 0);
        }
        __syncthreads();

        short8 af[4], bf[4];
        #pragma unroll
        for (int m = 0; m < 4; ++m) {
            int row = wr * 64 + m * 16 + l15;
            af[m] = *reinterpret_cast<const short8*>(As + row * 32 + kbr * 8);
        }
        #pragma unroll
        for (int n = 0; n < 4; ++n) {
            int row = wc * 64 + n * 16 + l15;
            bf[n] = *reinterpret_cast<const short8*>(Bs + row * 32 + kbr * 8);
        }
        #pragma unroll
        for (int m = 0; m < 4; ++m)
            #pragma unroll
            for (int n = 0; n < 4; ++n)
                acc[m][n] = __builtin_amdgcn_mfma_f32_16x16x32_bf16(
                    af[m], bf[n], acc[m][n], 0, 0, 0);
        __syncthreads();
    }

    // epilogue: C/D mapping col = lane&15, row = (lane>>4)*4 + reg
    int r0 = kbl * 4;
    #pragma unroll
    for (int m = 0; m < 4; ++m) {
        #pragma unroll
        for (int n = 0; n < 4; ++n) {
            int col = n0 + wc * 64 + n * 16 + l15;
            #pragma unroll
            for (int r = 0; r < 4; ++r) {
                int row = m0 + wr * 64 + m * 16 + r0 + r;
                float v = acc[m][n][r];
                if (mode == 0) {
                    ((float*)outp)[(size_t)row * N + col] = v;
                } else if (mode == 2) {
                    v += bias[col];
                    v = 0.5f * v * (1.f + erff(v * 0.70710678118654752f));
                    ((unsigned short*)outp)[(size_t)row * N + col] = f2bf(v);
                } else {
                    v += bias[col] + resid[(size_t)row * N + col];
                    ((float*)outp)[(size_t)row * N + col] = v;
                }
            }
        }
    }
}

// ---------------------------------------------------------------------------
// Fused windowed attention + LePE (fp32 math, bf16 output).
// grid = 1024 blocks of 128 threads: pid = wh*4 + qt
// ---------------------------------------------------------------------------
__global__ __launch_bounds__(128) void attn_kernel(
    const float* __restrict__ qkv,   // ROWS x 512 fp32
    const float* __restrict__ gw0, const float* __restrict__ gb0,
    const float* __restrict__ gw1, const float* __restrict__ gb1,
    unsigned short* __restrict__ att)  // ROWS x 256 bf16
{
    __shared__ float ks[128][32];
    __shared__ float vs[128][32];
    int pid  = blockIdx.x;
    int qt   = pid & 3;
    int wh   = pid >> 2;
    int br   = wh >> 7;
    int head = wh & 3;
    int win  = (wh >> 2) & 31;
    int bb   = win >> 3;
    int wi   = win & 7;
    int tid  = threadIdx.x;
    int qk_off = br * 128 + head * 32;
    int v_off  = 256 + qk_off;
    const float scale = 0.17677669529663689f;  // 32^-0.5

    int q   = qt * 128 + tid;
    int l_q = (br == 0) ? ((q >> 3) * 64 + wi * 8 + (q & 7)) : (wi * 512 + q);
    const float* qrow = qkv + ((size_t)(bb * 4096 + l_q)) * 512 + qk_off;
    float qreg[32];
    #pragma unroll
    for (int i = 0; i < 8; ++i) {
        float4 t = *reinterpret_cast<const float4*>(&qrow[i * 4]);
        qreg[i*4+0] = t.x * scale; qreg[i*4+1] = t.y * scale;
        qreg[i*4+2] = t.z * scale; qreg[i*4+3] = t.w * scale;
    }

    float m = -1e30f, s = 0.f;
    float acc[32];
    #pragma unroll
    for (int d = 0; d < 32; ++d) acc[d] = 0.f;

    for (int c = 0; c < 4; ++c) {
        #pragma unroll
        for (int i = 0; i < 8; ++i) {
            int idx = i * 128 + tid;     // 0..1023
            int row = idx >> 3, q4 = idx & 7;
            int kk  = c * 128 + row;
            int l   = (br == 0) ? ((kk >> 3) * 64 + wi * 8 + (kk & 7)) : (wi * 512 + kk);
            size_t base = ((size_t)(bb * 4096 + l)) * 512;
            *reinterpret_cast<float4*>(&ks[row][q4 * 4]) =
                *reinterpret_cast<const float4*>(&qkv[base + qk_off + q4 * 4]);
            *reinterpret_cast<float4*>(&vs[row][q4 * 4]) =
                *reinterpret_cast<const float4*>(&qkv[base + v_off + q4 * 4]);
        }
        __syncthreads();

        for (int kk = 0; kk < 128; kk += 4) {
            float d0 = 0.f, d1 = 0.f, d2 = 0.f, d3 = 0.f;
            #pragma unroll
            for (int d = 0; d < 32; ++d) {
                float qd = qreg[d];
                d0 += qd * ks[kk + 0][d];
                d1 += qd * ks[kk + 1][d];
                d2 += qd * ks[kk + 2][d];
                d3 += qd * ks[kk + 3][d];
            }
            float m4 = fmaxf(fmaxf(d0, d1), fmaxf(d2, d3));
            float nm = fmaxf(m, m4);
            float f  = __expf(m - nm);
            float p0 = __expf(d0 - nm), p1 = __expf(d1 - nm);
            float p2 = __expf(d2 - nm), p3 = __expf(d3 - nm);
            s = s * f + (p0 + p1) + (p2 + p3);
            #pragma unroll
            for (int d = 0; d < 32; ++d) {
                float a = acc[d] * f;
                a += p0 * vs[kk + 0][d];
                a += p1 * vs[kk + 1][d];
                a += p2 * vs[kk + 2][d];
                a += p3 * vs[kk + 3][d];
                acc[d] = a;
            }
            m = nm;
        }
        __syncthreads();
    }

    // epilogue: normalize + LePE (3x3 depthwise, per-window zero pad)
    float inv = 1.f / s;
    int Hsp = (br == 0) ? 64 : 8;
    int Wsp = (br == 0) ? 8 : 64;
    int hs  = (br == 0) ? (q >> 3) : (q >> 6);
    int wsx = (br == 0) ? (q & 7)  : (q & 63);
    const float* gw = br ? gw1 : gw0;
    const float* gb = br ? gb1 : gb0;
    #pragma unroll
    for (int d = 0; d < 32; ++d) acc[d] = acc[d] * inv + gb[head * 32 + d];

    #pragma unroll
    for (int dy = -1; dy <= 1; ++dy) {
        int hh = hs + dy;
        if (hh < 0 || hh >= Hsp) continue;
        #pragma unroll
        for (int dx = -1; dx <= 1; ++dx) {
            int ww = wsx + dx;
            if (ww < 0 || ww >= Wsp) continue;
            int l_n = (br == 0) ? (hh * 64 + wi * 8 + ww) : (wi * 512 + hh * 64 + ww);
            const float* vrow = qkv + ((size_t)(bb * 4096 + l_n)) * 512 + v_off;
            int t = (dy + 1) * 3 + (dx + 1);
            #pragma unroll
            for (int i = 0; i < 8; ++i) {
                float4 vv = *reinterpret_cast<const float4*>(&vrow[i * 4]);
                acc[i*4+0] += vv.x * gw[(head * 32 + i*4 + 0) * 9 + t];
                acc[i*4+1] += vv.y * gw[(head * 32 + i*4 + 1) * 9 + t];
                acc[i*4+2] += vv.z * gw[(head * 32 + i*4 + 2) * 9 + t];
                acc[i*4+3] += vv.w * gw[(head * 32 + i*4 + 3) * 9 + t];
            }
        }
    }

    unsigned short* orow = att + ((size_t)(bb * 4096 + l_q)) * 256 + br * 128 + head * 32;
    #pragma unroll
    for (int i = 0; i < 4; ++i) {
        unsigned int w0 = (unsigned int)f2bf(acc[i*8+0]) | ((unsigned int)f2bf(acc[i*8+1]) << 16);
        unsigned int w1 = (unsigned int)f2bf(acc[i*8+2]) | ((unsigned int)f2bf(acc[i*8+3]) << 16);
        unsigned int w2 = (unsigned int)f2bf(acc[i*8+4]) | ((unsigned int)f2bf(acc[i*8+5]) << 16);
        unsigned int w3 = (unsigned int)f2bf(acc[i*8+6]) | ((unsigned int)f2bf(acc[i*8+7]) << 16);
        *reinterpret_cast<uint4*>(orow + i * 8) = make_uint4(w0, w1, w2, w3);
    }
}

// ---------------------------------------------------------------------------
extern "C" void kernel_launch(void* const* d_in, const int* in_sizes, int n_in,
                              void* d_out, int out_size, void* d_ws, size_t ws_size,
                              hipStream_t stream) {
    const float* x     = (const float*)d_in[0];
    const float* n1w   = (const float*)d_in[1];
    const float* n1b   = (const float*)d_in[2];
    const float* qkvw  = (const float*)d_in[3];
    const float* gw0   = (const float*)d_in[4];
    const float* gb0   = (const float*)d_in[5];
    const float* gw1   = (const float*)d_in[6];
    const float* gb1   = (const float*)d_in[7];
    const float* projw = (const float*)d_in[8];
    const float* projb = (const float*)d_in[9];
    const float* n2w   = (const float*)d_in[10];
    const float* n2b   = (const float*)d_in[11];
    const float* fc1w  = (const float*)d_in[12];
    const float* fc1b  = (const float*)d_in[13];
    const float* fc2w  = (const float*)d_in[14];
    const float* fc2b  = (const float*)d_in[15];
    float* out = (float*)d_out;
    char* wsb  = (char*)d_ws;

    // workspace layout (bytes)
    float*          xT   = (float*)wsb;                          // 16,777,216 B
    float*          qkv  = (float*)(wsb + 16777216);             // 33,554,432 B
    unsigned short* img  = (unsigned short*)(wsb + 50331648);    //  8,388,608 B
    unsigned short* att  = (unsigned short*)(wsb + 58720256);    //  8,388,608 B
    unsigned short* wq   = (unsigned short*)(wsb + 67108864);    //   262,144 B
    unsigned short* wp   = (unsigned short*)(wsb + 67371008);    //   131,072 B
    unsigned short* w1   = (unsigned short*)(wsb + 67502080);    //   524,288 B
    unsigned short* w2   = (unsigned short*)(wsb + 68026368);    //   524,288 B
    unsigned short* ynorm  = img;                                // reuse
    unsigned short* hidden = (unsigned short*)qkv;               // reuse (33.5 MB)

    // weight fp32 -> bf16
    cvt_kernel<<<(131072/4 + 255)/256, 256, 0, stream>>>(qkvw, wq, 131072/4);
    cvt_kernel<<<( 65536/4 + 255)/256, 256, 0, stream>>>(projw, wp,  65536/4);
    cvt_kernel<<<(262144/4 + 255)/256, 256, 0, stream>>>(fc1w,  w1, 262144/4);
    cvt_kernel<<<(262144/4 + 255)/256, 256, 0, stream>>>(fc2w,  w2, 262144/4);

    // norm1 (+ raw fp32 transpose for residual), bf16 out
    norm_kernel<<<4096, 256, 0, stream>>>(x, n1w, n1b, img, xT, 1);
    // qkv = img @ qkv_w^T  -> fp32 (16384 x 512)
    mfma_gemm<<<dim3(4, 128), 256, 0, stream>>>(img, wq, nullptr, nullptr, qkv, 512, 256, 0);
    // windowed attention + LePE -> bf16 att
    attn_kernel<<<1024, 128, 0, stream>>>(qkv, gw0, gb0, gw1, gb1, att);
    // out = xT + att @ proj_w^T + proj_b  (fp32)
    mfma_gemm<<<dim3(2, 128), 256, 0, stream>>>(att, wp, projb, xT, out, 256, 256, 3);
    // norm2 -> bf16
    norm_kernel<<<4096, 256, 0, stream>>>(out, n2w, n2b, ynorm, nullptr, 0);
    // fc1: gelu -> bf16 hidden (16384 x 1024)
    mfma_gemm<<<dim3(8, 128), 256, 0, stream>>>(ynorm, w1, fc1b, nullptr, hidden, 1024, 256, 2);
    // fc2: + bias + resid(out) -> out (16384 x 256)
    mfma_gemm<<<dim3(2, 128), 256, 0, stream>>>(hidden, w2, fc2b, out, out, 256, 1024, 3);
}

// Round 5
// 283.491 us; speedup vs baseline: 4.1976x; 1.3480x over previous
//
#include <hip/hip_runtime.h>
#include <hip/hip_bf16.h>

// Problem geometry (fixed)
#define BDIM 4
#define CDIM 256
#define HDIM 64
#define WDIM 64
#define LDIM 4096   // H*W
#define ROWS 16384  // B*L

typedef __attribute__((ext_vector_type(8))) short short8;
typedef __attribute__((ext_vector_type(4))) float f32x4;
typedef __attribute__((ext_vector_type(16))) float f32x16;
typedef unsigned int u32;

static __device__ __forceinline__ unsigned short f2bf(float f) {
    unsigned int x = __float_as_uint(f);
    unsigned int r = (x + 0x7fffu + ((x >> 16) & 1u)) >> 16;   // RNE
    return (unsigned short)r;
}
static __device__ __forceinline__ float bf2f(unsigned int u) {
    return __uint_as_float(u << 16);
}
static __device__ __forceinline__ u32 pk2(float a, float b) {
    return (u32)f2bf(a) | ((u32)f2bf(b) << 16);
}

// ---------------------------------------------------------------------------
// fp32 -> bf16 conversion (weights), float4-vectorized, n4 = n/4
// ---------------------------------------------------------------------------
__global__ __launch_bounds__(256) void cvt_kernel(
    const float* __restrict__ in, unsigned short* __restrict__ out, int n4)
{
    int i = blockIdx.x * 256 + threadIdx.x;
    if (i >= n4) return;
    float4 f = reinterpret_cast<const float4*>(in)[i];
    reinterpret_cast<uint2*>(out)[i] = make_uint2(pk2(f.x, f.y), pk2(f.z, f.w));
}

// ---------------------------------------------------------------------------
// LayerNorm over C=256 -> bf16 out (+ optional raw fp32 transpose copy xT).
// ---------------------------------------------------------------------------
__global__ __launch_bounds__(256) void norm_kernel(
    const float* __restrict__ xin,
    const float* __restrict__ w, const float* __restrict__ b,
    unsigned short* __restrict__ out,
    float* __restrict__ xT,
    int transposed_in)
{
    int wave = threadIdx.x >> 6;
    int lane = threadIdx.x & 63;
    int row = blockIdx.x * 4 + wave;
    float v[4];
    float sum = 0.f, sumsq = 0.f;
    if (transposed_in) {
        int bb = row >> 12;
        int l = row & 4095;
        const float* xb = xin + (size_t)bb * (CDIM * LDIM) + l;
        #pragma unroll
        for (int i = 0; i < 4; ++i) {
            int c = lane + i * 64;
            float t = xb[(size_t)c * LDIM];
            v[i] = t; sum += t; sumsq += t * t;
        }
    } else {
        const float* xr = xin + (size_t)row * CDIM;
        #pragma unroll
        for (int i = 0; i < 4; ++i) {
            float t = xr[lane + i * 64];
            v[i] = t; sum += t; sumsq += t * t;
        }
    }
    #pragma unroll
    for (int off = 32; off > 0; off >>= 1) {
        sum   += __shfl_xor(sum, off);
        sumsq += __shfl_xor(sumsq, off);
    }
    float mean = sum * (1.f / 256.f);
    float var  = sumsq * (1.f / 256.f) - mean * mean;
    float inv  = rsqrtf(var + 1e-5f);
    unsigned short* orow = out + (size_t)row * CDIM;
    #pragma unroll
    for (int i = 0; i < 4; ++i) {
        int c = lane + i * 64;
        if (xT) xT[(size_t)row * CDIM + c] = v[i];
        orow[c] = f2bf((v[i] - mean) * inv * w[c] + b[c]);
    }
}

// ---------------------------------------------------------------------------
// bf16 MFMA GEMM: C = A @ B^T (+ bias / gelu / resid), fp32 accumulate.
// 128x128 tile, BK=32, 4 waves, 16x16x32 frags. global_load_lds staging with
// both-sides XOR swizzle.
// mode: 0 plain->f32; 1 plain->bf16; 2 +bias,gelu->bf16; 3 +bias+resid->f32
// ---------------------------------------------------------------------------
__global__ __launch_bounds__(256) void mfma_gemm(
    const unsigned short* __restrict__ A,
    const unsigned short* __restrict__ Bm,
    const float* __restrict__ bias,
    const float* __restrict__ resid,
    void* __restrict__ outp,
    int N, int K, int mode)
{
    __shared__ unsigned short As[128 * 32];
    __shared__ unsigned short Bs[128 * 32];
    int tid  = threadIdx.x;
    int lane = tid & 63;
    int w    = tid >> 6;
    int wr   = w >> 1, wc = w & 1;
    int l15  = lane & 15, kbl = lane >> 4;
    int n0 = blockIdx.x * 128, m0 = blockIdx.y * 128;

    f32x4 acc[4][4];
    #pragma unroll
    for (int m = 0; m < 4; ++m)
        #pragma unroll
        for (int n = 0; n < 4; ++n)
            acc[m][n] = (f32x4){0.f, 0.f, 0.f, 0.f};

    int kbr = kbl ^ (l15 & 3);

    for (int k0 = 0; k0 < K; k0 += 32) {
        #pragma unroll
        for (int i = 0; i < 2; ++i) {
            int c = i * 256 + tid;
            int row = c >> 2, kbp = c & 3;
            int cbg = kbp ^ (row & 3);
            const unsigned short* ga = A  + (size_t)(m0 + row) * K + k0 + cbg * 8;
            const unsigned short* gb = Bm + (size_t)(n0 + row) * K + k0 + cbg * 8;
            __builtin_amdgcn_global_load_lds(
                (const __attribute__((address_space(1))) void*)ga,
                (__attribute__((address_space(3))) void*)(As + c * 8), 16, 0, 0);
            __builtin_amdgcn_global_load_lds(
                (const __attribute__((address_space(1))) void*)gb,
                (__attribute__((address_space(3))) void*)(Bs + c * 8), 16, 0, 0);
        }
        __syncthreads();

        short8 af[4], bf[4];
        #pragma unroll
        for (int m = 0; m < 4; ++m) {
            int row = wr * 64 + m * 16 + l15;
            af[m] = *reinterpret_cast<const short8*>(As + row * 32 + kbr * 8);
        }
        #pragma unroll
        for (int n = 0; n < 4; ++n) {
            int row = wc * 64 + n * 16 + l15;
            bf[n] = *reinterpret_cast<const short8*>(Bs + row * 32 + kbr * 8);
        }
        #pragma unroll
        for (int m = 0; m < 4; ++m)
            #pragma unroll
            for (int n = 0; n < 4; ++n)
                acc[m][n] = __builtin_amdgcn_mfma_f32_16x16x32_bf16(
                    af[m], bf[n], acc[m][n], 0, 0, 0);
        __syncthreads();
    }

    int r0 = kbl * 4;
    #pragma unroll
    for (int m = 0; m < 4; ++m) {
        #pragma unroll
        for (int n = 0; n < 4; ++n) {
            int col = n0 + wc * 64 + n * 16 + l15;
            #pragma unroll
            for (int r = 0; r < 4; ++r) {
                int row = m0 + wr * 64 + m * 16 + r0 + r;
                float v = acc[m][n][r];
                if (mode == 0) {
                    ((float*)outp)[(size_t)row * N + col] = v;
                } else if (mode == 1) {
                    ((unsigned short*)outp)[(size_t)row * N + col] = f2bf(v);
                } else if (mode == 2) {
                    v += bias[col];
                    v = 0.5f * v * (1.f + erff(v * 0.70710678118654752f));
                    ((unsigned short*)outp)[(size_t)row * N + col] = f2bf(v);
                } else {
                    v += bias[col] + resid[(size_t)row * N + col];
                    ((float*)outp)[(size_t)row * N + col] = v;
                }
            }
        }
    }
}

// ---------------------------------------------------------------------------
// MFMA windowed attention (no LePE). One block per (window, head): 512 thr.
// Swapped QK^T: S-frag = mfma(K,Q) -> lane owns q=lane&31, 16 key-scores.
// Online softmax fully lane-local; P->bf16 + partner shfl builds PV B-frags;
// swapped PV: O = mfma(Vt, P) keeps q as the output column (rescale is
// lane-local). K (pre-scaled by sqrt(scale)) and V^T staged in LDS, 64 KB,
// both-sides XOR slot swizzles. No inner-loop barriers.
// ---------------------------------------------------------------------------
__global__ __launch_bounds__(512) void attn_kernel(
    const unsigned short* __restrict__ qkv,   // ROWS x 512 bf16
    unsigned short* __restrict__ att)         // ROWS x 256 bf16
{
    __shared__ unsigned short Kbuf[512 * 32]; // [row][d], slot ^= (row>>1)&3
    __shared__ unsigned short Vt[32 * 512];   // [d][key], slot ^= d&7
    const int wh = blockIdx.x;
    const int br = wh >> 7, head = wh & 3, win = (wh >> 2) & 31;
    const int bb = win >> 3, wi = win & 7;
    const int tid = threadIdx.x;
    const int qk_off = br * 128 + head * 32;
    const int v_off = 256 + qk_off;
    const float sscale = 0.42044820762685725f;  // 32^-0.25 = sqrt(scale)

    // ---- stage K (scaled) ----
    {
        int t = tid;
        int l = (br == 0) ? ((t >> 3) * 64 + wi * 8 + (t & 7)) : (wi * 512 + t);
        const unsigned short* src = qkv + ((size_t)(bb * 4096 + l)) * 512 + qk_off;
        #pragma unroll
        for (int s = 0; s < 4; ++s) {
            uint4 raw = *reinterpret_cast<const uint4*>(src + s * 8);
            u32 rw[4] = {raw.x, raw.y, raw.z, raw.w};
            u32 ow[4];
            #pragma unroll
            for (int i = 0; i < 4; ++i) {
                float lo = bf2f(rw[i] & 0xffffu) * sscale;
                float hi = bf2f(rw[i] >> 16) * sscale;
                ow[i] = pk2(lo, hi);
            }
            int sl = s ^ ((t >> 1) & 3);
            *reinterpret_cast<uint4*>(Kbuf + t * 32 + sl * 8) =
                make_uint4(ow[0], ow[1], ow[2], ow[3]);
        }
    }
    // ---- stage V transposed ----
    {
        int kp = (tid & 255) * 2, dh = tid >> 8;
        int kq = kp + 1;
        int l0 = (br == 0) ? ((kp >> 3) * 64 + wi * 8 + (kp & 7)) : (wi * 512 + kp);
        int l1 = (br == 0) ? ((kq >> 3) * 64 + wi * 8 + (kq & 7)) : (wi * 512 + kq);
        const unsigned short* v0 = qkv + ((size_t)(bb * 4096 + l0)) * 512 + v_off + dh * 16;
        const unsigned short* v1 = qkv + ((size_t)(bb * 4096 + l1)) * 512 + v_off + dh * 16;
        uint4 a0 = *reinterpret_cast<const uint4*>(v0);
        uint4 a1 = *reinterpret_cast<const uint4*>(v0 + 8);
        uint4 b0 = *reinterpret_cast<const uint4*>(v1);
        uint4 b1 = *reinterpret_cast<const uint4*>(v1 + 8);
        u32 av[8] = {a0.x, a0.y, a0.z, a0.w, a1.x, a1.y, a1.z, a1.w};
        u32 bv[8] = {b0.x, b0.y, b0.z, b0.w, b1.x, b1.y, b1.z, b1.w};
        int slot = kp >> 3;
        #pragma unroll
        for (int dd = 0; dd < 16; ++dd) {
            u32 x0 = (dd & 1) ? (av[dd >> 1] >> 16) : (av[dd >> 1] & 0xffffu);
            u32 x1 = (dd & 1) ? (bv[dd >> 1] >> 16) : (bv[dd >> 1] & 0xffffu);
            int d = dh * 16 + dd;
            int sl = slot ^ (d & 7);
            *reinterpret_cast<u32*>(Vt + d * 512 + sl * 8 + (kp & 7)) = x0 | (x1 << 16);
        }
    }
    __syncthreads();

    const int lane = tid & 63;
    const int w = tid >> 6;
    const int ql = lane & 31;
    const int h = lane >> 5;
    const int q0 = w * 64;

    f32x16 O0, O1;
    #pragma unroll
    for (int i = 0; i < 16; ++i) { O0[i] = 0.f; O1[i] = 0.f; }
    float m0 = -1e30f, m1 = -1e30f, su0 = 0.f, su1 = 0.f;

    auto process = [&](int QS, f32x16& O, float& M, float& SU,
                       short8 kf0, short8 kf1, short8 vf0, short8 vf1, int k0) {
        int qrow = q0 + QS * 32 + ql;
        int sw = (qrow >> 1) & 3;
        short8 qf0 = *reinterpret_cast<const short8*>(Kbuf + qrow * 32 + ((0 + h) ^ sw) * 8);
        short8 qf1 = *reinterpret_cast<const short8*>(Kbuf + qrow * 32 + ((2 + h) ^ sw) * 8);
        f32x16 sacc;
        #pragma unroll
        for (int i = 0; i < 16; ++i) sacc[i] = 0.f;
        sacc = __builtin_amdgcn_mfma_f32_32x32x16_bf16(kf0, qf0, sacc, 0, 0, 0);
        sacc = __builtin_amdgcn_mfma_f32_32x32x16_bf16(kf1, qf1, sacc, 0, 0, 0);
        float mx = sacc[0];
        #pragma unroll
        for (int r = 1; r < 16; ++r) mx = fmaxf(mx, sacc[r]);
        mx = fmaxf(mx, __shfl_xor(mx, 32));
        float nm = fmaxf(M, mx);
        float fs = __expf(M - nm);
        M = nm;
        float p[16];
        float ps = 0.f;
        #pragma unroll
        for (int r = 0; r < 16; ++r) { p[r] = __expf(sacc[r] - nm); ps += p[r]; }
        ps += __shfl_xor(ps, 32);
        SU = SU * fs + ps;
        u32 P[8];
        #pragma unroll
        for (int g = 0; g < 4; ++g) {
            P[2 * g]     = pk2(p[4 * g],     p[4 * g + 1]);
            P[2 * g + 1] = pk2(p[4 * g + 2], p[4 * g + 3]);
        }
        u32 X[8];
        #pragma unroll
        for (int i = 0; i < 8; ++i) X[i] = __shfl_xor(P[i], 32);
        union { u32 u[4]; short8 s; } c0, c1;
        c0.u[0] = h ? X[2] : P[0];  c0.u[1] = h ? X[3] : P[1];
        c0.u[2] = h ? P[2] : X[0];  c0.u[3] = h ? P[3] : X[1];
        c1.u[0] = h ? X[6] : P[4];  c1.u[1] = h ? X[7] : P[5];
        c1.u[2] = h ? P[6] : X[4];  c1.u[3] = h ? P[7] : X[5];
        #pragma unroll
        for (int r = 0; r < 16; ++r) O[r] *= fs;
        O = __builtin_amdgcn_mfma_f32_32x32x16_bf16(vf0, c0.s, O, 0, 0, 0);
        O = __builtin_amdgcn_mfma_f32_32x32x16_bf16(vf1, c1.s, O, 0, 0, 0);
    };

    for (int kt = 0; kt < 16; ++kt) {
        int k0 = kt * 32;
        int krow = k0 + ql;
        int ksw = (krow >> 1) & 3;
        short8 kf0 = *reinterpret_cast<const short8*>(Kbuf + krow * 32 + ((0 + h) ^ ksw) * 8);
        short8 kf1 = *reinterpret_cast<const short8*>(Kbuf + krow * 32 + ((2 + h) ^ ksw) * 8);
        int ko0 = k0 + h * 8;
        int ko1 = k0 + 16 + h * 8;
        short8 vf0 = *reinterpret_cast<const short8*>(Vt + ql * 512 + ((ko0 >> 3) ^ (ql & 7)) * 8);
        short8 vf1 = *reinterpret_cast<const short8*>(Vt + ql * 512 + ((ko1 >> 3) ^ (ql & 7)) * 8);
        process(0, O0, m0, su0, kf0, kf1, vf0, vf1, k0);
        process(1, O1, m1, su1, kf0, kf1, vf0, vf1, k0);
    }

    // epilogue: normalize, write. lane's O reg r -> d = (r&3) + 8*(r>>2) + 4h
    #pragma unroll
    for (int QS = 0; QS < 2; ++QS) {
        f32x16& O = QS ? O1 : O0;
        float inv = 1.f / (QS ? su1 : su0);
        int qrow = q0 + QS * 32 + ql;
        int l = (br == 0) ? ((qrow >> 3) * 64 + wi * 8 + (qrow & 7)) : (wi * 512 + qrow);
        unsigned short* orow = att + ((size_t)(bb * 4096 + l)) * 256 + qk_off;
        #pragma unroll
        for (int g = 0; g < 4; ++g) {
            u32 lo = pk2(O[4 * g] * inv, O[4 * g + 1] * inv);
            u32 hi = pk2(O[4 * g + 2] * inv, O[4 * g + 3] * inv);
            *reinterpret_cast<uint2*>(orow + 8 * g + 4 * h) = make_uint2(lo, hi);
        }
    }
}

// ---------------------------------------------------------------------------
// LePE: att += depthwise3x3(V) + gb, per-window zero pad. 8 ch per thread.
// ---------------------------------------------------------------------------
__global__ __launch_bounds__(256) void lepe_kernel(
    const unsigned short* __restrict__ qkv,
    const float* __restrict__ gw0, const float* __restrict__ gb0,
    const float* __restrict__ gw1, const float* __restrict__ gb1,
    unsigned short* __restrict__ att)
{
    int idx = blockIdx.x * 256 + threadIdx.x;   // ROWS*32 total
    int row = idx >> 5;
    int chg = (idx & 31) * 8;
    int bb = row >> 12, l = row & 4095;
    int hh = l >> 6, ww = l & 63;
    int br = chg >> 7;
    int chl = chg & 127;
    const float* gw = br ? gw1 : gw0;
    const float* gb = br ? gb1 : gb0;

    float acc[8];
    uint4 a = *reinterpret_cast<const uint4*>(att + (size_t)row * 256 + chg);
    u32 aw[4] = {a.x, a.y, a.z, a.w};
    #pragma unroll
    for (int i = 0; i < 8; ++i)
        acc[i] = bf2f((i & 1) ? (aw[i >> 1] >> 16) : (aw[i >> 1] & 0xffffu)) + gb[chl + i];

    #pragma unroll
    for (int dy = -1; dy <= 1; ++dy) {
        int hn = hh + dy;
        bool okh = (br == 0) ? ((unsigned)hn < 64u) : ((unsigned)((hh & 7) + dy) < 8u);
        if (!okh) continue;
        #pragma unroll
        for (int dx = -1; dx <= 1; ++dx) {
            int wn = ww + dx;
            bool okw = (br == 0) ? ((unsigned)((ww & 7) + dx) < 8u) : ((unsigned)wn < 64u);
            if (!okw) continue;
            int nrow = bb * 4096 + hn * 64 + wn;
            uint4 vq = *reinterpret_cast<const uint4*>(qkv + (size_t)nrow * 512 + 256 + chg);
            u32 vw[4] = {vq.x, vq.y, vq.z, vq.w};
            int t = (dy + 1) * 3 + (dx + 1);
            #pragma unroll
            for (int i = 0; i < 8; ++i) {
                float vv = bf2f((i & 1) ? (vw[i >> 1] >> 16) : (vw[i >> 1] & 0xffffu));
                acc[i] += vv * gw[(chl + i) * 9 + t];
            }
        }
    }
    uint4 o;
    o.x = pk2(acc[0], acc[1]); o.y = pk2(acc[2], acc[3]);
    o.z = pk2(acc[4], acc[5]); o.w = pk2(acc[6], acc[7]);
    *reinterpret_cast<uint4*>(att + (size_t)row * 256 + chg) = o;
}

// ---------------------------------------------------------------------------
extern "C" void kernel_launch(void* const* d_in, const int* in_sizes, int n_in,
                              void* d_out, int out_size, void* d_ws, size_t ws_size,
                              hipStream_t stream) {
    const float* x     = (const float*)d_in[0];
    const float* n1w   = (const float*)d_in[1];
    const float* n1b   = (const float*)d_in[2];
    const float* qkvw  = (const float*)d_in[3];
    const float* gw0   = (const float*)d_in[4];
    const float* gb0   = (const float*)d_in[5];
    const float* gw1   = (const float*)d_in[6];
    const float* gb1   = (const float*)d_in[7];
    const float* projw = (const float*)d_in[8];
    const float* projb = (const float*)d_in[9];
    const float* n2w   = (const float*)d_in[10];
    const float* n2b   = (const float*)d_in[11];
    const float* fc1w  = (const float*)d_in[12];
    const float* fc1b  = (const float*)d_in[13];
    const float* fc2w  = (const float*)d_in[14];
    const float* fc2b  = (const float*)d_in[15];
    float* out = (float*)d_out;
    char* wsb  = (char*)d_ws;

    // workspace layout (bytes)
    float*          xT   = (float*)wsb;                          // 16,777,216
    unsigned short* qkv  = (unsigned short*)(wsb + 16777216);    // 16,777,216
    unsigned short* att  = (unsigned short*)(wsb + 33554432);    //  8,388,608
    unsigned short* img  = (unsigned short*)(wsb + 41943040);    //  8,388,608
    unsigned short* wq   = (unsigned short*)(wsb + 50331648);    //    262,144
    unsigned short* wp   = (unsigned short*)(wsb + 50593792);    //    131,072
    unsigned short* w1   = (unsigned short*)(wsb + 50724864);    //    524,288
    unsigned short* w2   = (unsigned short*)(wsb + 51249152);    //    524,288
    unsigned short* ynorm  = img;                                // reuse
    unsigned short* hidden = (unsigned short*)wsb;               // overlays xT+qkv (dead by fc1)

    // weight fp32 -> bf16
    cvt_kernel<<<(131072/4 + 255)/256, 256, 0, stream>>>(qkvw, wq, 131072/4);
    cvt_kernel<<<( 65536/4 + 255)/256, 256, 0, stream>>>(projw, wp,  65536/4);
    cvt_kernel<<<(262144/4 + 255)/256, 256, 0, stream>>>(fc1w,  w1, 262144/4);
    cvt_kernel<<<(262144/4 + 255)/256, 256, 0, stream>>>(fc2w,  w2, 262144/4);

    // norm1 (+ raw fp32 transpose for residual), bf16 out
    norm_kernel<<<4096, 256, 0, stream>>>(x, n1w, n1b, img, xT, 1);
    // qkv = img @ qkv_w^T -> bf16 (16384 x 512)
    mfma_gemm<<<dim3(4, 128), 256, 0, stream>>>(img, wq, nullptr, nullptr, qkv, 512, 256, 1);
    // MFMA windowed attention -> bf16 att
    attn_kernel<<<256, 512, 0, stream>>>(qkv, att);
    // att += LePE(V) + gb
    lepe_kernel<<<2048, 256, 0, stream>>>(qkv, gw0, gb0, gw1, gb1, att);
    // out = xT + att @ proj_w^T + proj_b (fp32)
    mfma_gemm<<<dim3(2, 128), 256, 0, stream>>>(att, wp, projb, xT, out, 256, 256, 3);
    // norm2 -> bf16
    norm_kernel<<<4096, 256, 0, stream>>>(out, n2w, n2b, ynorm, nullptr, 0);
    // fc1: gelu -> bf16 hidden (16384 x 1024)
    mfma_gemm<<<dim3(8, 128), 256, 0, stream>>>(ynorm, w1, fc1b, nullptr, hidden, 1024, 256, 2);
    // fc2: + bias + resid(out) -> out (16384 x 256)
    mfma_gemm<<<dim3(2, 128), 256, 0, stream>>>(hidden, w2, fc2b, out, out, 256, 1024, 3);
}

// Round 6
// 228.051 us; speedup vs baseline: 5.2180x; 1.2431x over previous
//
#include <hip/hip_runtime.h>
#include <hip/hip_bf16.h>

// Problem geometry (fixed)
#define BDIM 4
#define CDIM 256
#define HDIM 64
#define WDIM 64
#define LDIM 4096   // H*W
#define ROWS 16384  // B*L

typedef __attribute__((ext_vector_type(8))) short short8;
typedef __attribute__((ext_vector_type(4))) float f32x4;
typedef __attribute__((ext_vector_type(16))) float f32x16;
typedef unsigned int u32;

static __device__ __forceinline__ unsigned short f2bf(float f) {
    unsigned int x = __float_as_uint(f);
    unsigned int r = (x + 0x7fffu + ((x >> 16) & 1u)) >> 16;   // RNE
    return (unsigned short)r;
}
static __device__ __forceinline__ float bf2f(unsigned int u) {
    return __uint_as_float(u << 16);
}
static __device__ __forceinline__ u32 pk2(float a, float b) {
    return (u32)f2bf(a) | ((u32)f2bf(b) << 16);
}

// ---------------------------------------------------------------------------
// fp32 -> bf16 conversion (weights), float4-vectorized, n4 = n/4
// ---------------------------------------------------------------------------
__global__ __launch_bounds__(256) void cvt_kernel(
    const float* __restrict__ in, unsigned short* __restrict__ out, int n4)
{
    int i = blockIdx.x * 256 + threadIdx.x;
    if (i >= n4) return;
    float4 f = reinterpret_cast<const float4*>(in)[i];
    reinterpret_cast<uint2*>(out)[i] = make_uint2(pk2(f.x, f.y), pk2(f.z, f.w));
}

// ---------------------------------------------------------------------------
// LayerNorm over C=256 -> bf16 out (+ optional raw fp32 transpose copy xT).
// ---------------------------------------------------------------------------
__global__ __launch_bounds__(256) void norm_kernel(
    const float* __restrict__ xin,
    const float* __restrict__ w, const float* __restrict__ b,
    unsigned short* __restrict__ out,
    float* __restrict__ xT,
    int transposed_in)
{
    int wave = threadIdx.x >> 6;
    int lane = threadIdx.x & 63;
    int row = blockIdx.x * 4 + wave;
    float v[4];
    float sum = 0.f, sumsq = 0.f;
    if (transposed_in) {
        int bb = row >> 12;
        int l = row & 4095;
        const float* xb = xin + (size_t)bb * (CDIM * LDIM) + l;
        #pragma unroll
        for (int i = 0; i < 4; ++i) {
            int c = lane + i * 64;
            float t = xb[(size_t)c * LDIM];
            v[i] = t; sum += t; sumsq += t * t;
        }
    } else {
        const float* xr = xin + (size_t)row * CDIM;
        #pragma unroll
        for (int i = 0; i < 4; ++i) {
            float t = xr[lane + i * 64];
            v[i] = t; sum += t; sumsq += t * t;
        }
    }
    #pragma unroll
    for (int off = 32; off > 0; off >>= 1) {
        sum   += __shfl_xor(sum, off);
        sumsq += __shfl_xor(sumsq, off);
    }
    float mean = sum * (1.f / 256.f);
    float var  = sumsq * (1.f / 256.f) - mean * mean;
    float inv  = rsqrtf(var + 1e-5f);
    unsigned short* orow = out + (size_t)row * CDIM;
    #pragma unroll
    for (int i = 0; i < 4; ++i) {
        int c = lane + i * 64;
        if (xT) xT[(size_t)row * CDIM + c] = v[i];
        orow[c] = f2bf((v[i] - mean) * inv * w[c] + b[c]);
    }
}

// ---------------------------------------------------------------------------
// bf16 MFMA GEMM: C = A @ B^T (+ bias / gelu / resid), fp32 accumulate.
// 128x128 tile, BK=32, 4 waves, 16x16x32 frags. global_load_lds staging with
// both-sides XOR swizzle.
// mode: 0 plain->f32; 1 plain->bf16; 2 +bias,gelu->bf16; 3 +bias+resid->f32
// ---------------------------------------------------------------------------
__global__ __launch_bounds__(256) void mfma_gemm(
    const unsigned short* __restrict__ A,
    const unsigned short* __restrict__ Bm,
    const float* __restrict__ bias,
    const float* __restrict__ resid,
    void* __restrict__ outp,
    int N, int K, int mode)
{
    __shared__ unsigned short As[128 * 32];
    __shared__ unsigned short Bs[128 * 32];
    int tid  = threadIdx.x;
    int lane = tid & 63;
    int w    = tid >> 6;
    int wr   = w >> 1, wc = w & 1;
    int l15  = lane & 15, kbl = lane >> 4;
    int n0 = blockIdx.x * 128, m0 = blockIdx.y * 128;

    f32x4 acc[4][4];
    #pragma unroll
    for (int m = 0; m < 4; ++m)
        #pragma unroll
        for (int n = 0; n < 4; ++n)
            acc[m][n] = (f32x4){0.f, 0.f, 0.f, 0.f};

    int kbr = kbl ^ (l15 & 3);

    for (int k0 = 0; k0 < K; k0 += 32) {
        #pragma unroll
        for (int i = 0; i < 2; ++i) {
            int c = i * 256 + tid;
            int row = c >> 2, kbp = c & 3;
            int cbg = kbp ^ (row & 3);
            const unsigned short* ga = A  + (size_t)(m0 + row) * K + k0 + cbg * 8;
            const unsigned short* gb = Bm + (size_t)(n0 + row) * K + k0 + cbg * 8;
            __builtin_amdgcn_global_load_lds(
                (const __attribute__((address_space(1))) void*)ga,
                (__attribute__((address_space(3))) void*)(As + c * 8), 16, 0, 0);
            __builtin_amdgcn_global_load_lds(
                (const __attribute__((address_space(1))) void*)gb,
                (__attribute__((address_space(3))) void*)(Bs + c * 8), 16, 0, 0);
        }
        __syncthreads();

        short8 af[4], bf[4];
        #pragma unroll
        for (int m = 0; m < 4; ++m) {
            int row = wr * 64 + m * 16 + l15;
            af[m] = *reinterpret_cast<const short8*>(As + row * 32 + kbr * 8);
        }
        #pragma unroll
        for (int n = 0; n < 4; ++n) {
            int row = wc * 64 + n * 16 + l15;
            bf[n] = *reinterpret_cast<const short8*>(Bs + row * 32 + kbr * 8);
        }
        #pragma unroll
        for (int m = 0; m < 4; ++m)
            #pragma unroll
            for (int n = 0; n < 4; ++n)
                acc[m][n] = __builtin_amdgcn_mfma_f32_16x16x32_bf16(
                    af[m], bf[n], acc[m][n], 0, 0, 0);
        __syncthreads();
    }

    int r0 = kbl * 4;
    #pragma unroll
    for (int m = 0; m < 4; ++m) {
        #pragma unroll
        for (int n = 0; n < 4; ++n) {
            int col = n0 + wc * 64 + n * 16 + l15;
            #pragma unroll
            for (int r = 0; r < 4; ++r) {
                int row = m0 + wr * 64 + m * 16 + r0 + r;
                float v = acc[m][n][r];
                if (mode == 0) {
                    ((float*)outp)[(size_t)row * N + col] = v;
                } else if (mode == 1) {
                    ((unsigned short*)outp)[(size_t)row * N + col] = f2bf(v);
                } else if (mode == 2) {
                    v += bias[col];
                    v = 0.5f * v * (1.f + erff(v * 0.70710678118654752f));
                    ((unsigned short*)outp)[(size_t)row * N + col] = f2bf(v);
                } else {
                    v += bias[col] + resid[(size_t)row * N + col];
                    ((float*)outp)[(size_t)row * N + col] = v;
                }
            }
        }
    }
}

// ---------------------------------------------------------------------------
// MFMA windowed attention + fused LePE. One block per (window, head): 512 thr.
// Swapped QK^T: S-frag = mfma(K,Q) -> lane owns q=lane&31, 16 key-scores.
// Online softmax lane-local; P->bf16 + partner shfl builds PV B-frags;
// swapped PV: O = mfma(Vt, P). K (pre-scaled) and V^T staged in LDS with
// both-sides XOR slot swizzles. LePE 3x3 depthwise computed in the epilogue
// entirely from the LDS V^T tile + LDS-staged weights (per-window zero pad).
// ---------------------------------------------------------------------------
__global__ __launch_bounds__(512) void attn_kernel(
    const unsigned short* __restrict__ qkv,   // ROWS x 512 bf16
    const float* __restrict__ gw0, const float* __restrict__ gb0,
    const float* __restrict__ gw1, const float* __restrict__ gb1,
    unsigned short* __restrict__ att)         // ROWS x 256 bf16
{
    __shared__ unsigned short Kbuf[512 * 32]; // [row][d], slot ^= (row>>1)&3
    __shared__ unsigned short Vt[32 * 512];   // [d][key], slot ^= d&7
    __shared__ float gwl[288];                // this head's 32ch x 9 taps
    __shared__ float gbl[32];
    const int wh = blockIdx.x;
    const int br = wh >> 7, head = wh & 3, win = (wh >> 2) & 31;
    const int bb = win >> 3, wi = win & 7;
    const int tid = threadIdx.x;
    const int qk_off = br * 128 + head * 32;
    const int v_off = 256 + qk_off;
    const float sscale = 0.42044820762685725f;  // 32^-0.25 = sqrt(scale)

    // ---- stage LePE weights (head's 32-channel slice) ----
    {
        const float* gw = br ? gw1 : gw0;
        const float* gb = br ? gb1 : gb0;
        if (tid < 288) gwl[tid] = gw[(head * 32) * 9 + tid];
        else if (tid >= 480) gbl[tid - 480] = gb[head * 32 + tid - 480];
    }
    // ---- stage K (scaled) ----
    {
        int t = tid;
        int l = (br == 0) ? ((t >> 3) * 64 + wi * 8 + (t & 7)) : (wi * 512 + t);
        const unsigned short* src = qkv + ((size_t)(bb * 4096 + l)) * 512 + qk_off;
        #pragma unroll
        for (int s = 0; s < 4; ++s) {
            uint4 raw = *reinterpret_cast<const uint4*>(src + s * 8);
            u32 rw[4] = {raw.x, raw.y, raw.z, raw.w};
            u32 ow[4];
            #pragma unroll
            for (int i = 0; i < 4; ++i) {
                float lo = bf2f(rw[i] & 0xffffu) * sscale;
                float hi = bf2f(rw[i] >> 16) * sscale;
                ow[i] = pk2(lo, hi);
            }
            int sl = s ^ ((t >> 1) & 3);
            *reinterpret_cast<uint4*>(Kbuf + t * 32 + sl * 8) =
                make_uint4(ow[0], ow[1], ow[2], ow[3]);
        }
    }
    // ---- stage V transposed ----
    {
        int kp = (tid & 255) * 2, dh = tid >> 8;
        int kq = kp + 1;
        int l0 = (br == 0) ? ((kp >> 3) * 64 + wi * 8 + (kp & 7)) : (wi * 512 + kp);
        int l1 = (br == 0) ? ((kq >> 3) * 64 + wi * 8 + (kq & 7)) : (wi * 512 + kq);
        const unsigned short* v0 = qkv + ((size_t)(bb * 4096 + l0)) * 512 + v_off + dh * 16;
        const unsigned short* v1 = qkv + ((size_t)(bb * 4096 + l1)) * 512 + v_off + dh * 16;
        uint4 a0 = *reinterpret_cast<const uint4*>(v0);
        uint4 a1 = *reinterpret_cast<const uint4*>(v0 + 8);
        uint4 b0 = *reinterpret_cast<const uint4*>(v1);
        uint4 b1 = *reinterpret_cast<const uint4*>(v1 + 8);
        u32 av[8] = {a0.x, a0.y, a0.z, a0.w, a1.x, a1.y, a1.z, a1.w};
        u32 bv[8] = {b0.x, b0.y, b0.z, b0.w, b1.x, b1.y, b1.z, b1.w};
        int slot = kp >> 3;
        #pragma unroll
        for (int dd = 0; dd < 16; ++dd) {
            u32 x0 = (dd & 1) ? (av[dd >> 1] >> 16) : (av[dd >> 1] & 0xffffu);
            u32 x1 = (dd & 1) ? (bv[dd >> 1] >> 16) : (bv[dd >> 1] & 0xffffu);
            int d = dh * 16 + dd;
            int sl = slot ^ (d & 7);
            *reinterpret_cast<u32*>(Vt + d * 512 + sl * 8 + (kp & 7)) = x0 | (x1 << 16);
        }
    }
    __syncthreads();

    const int lane = tid & 63;
    const int w = tid >> 6;
    const int ql = lane & 31;
    const int h = lane >> 5;
    const int q0 = w * 64;

    f32x16 O0, O1;
    #pragma unroll
    for (int i = 0; i < 16; ++i) { O0[i] = 0.f; O1[i] = 0.f; }
    float m0 = -1e30f, m1 = -1e30f, su0 = 0.f, su1 = 0.f;

    auto process = [&](int QS, f32x16& O, float& M, float& SU,
                       short8 kf0, short8 kf1, short8 vf0, short8 vf1) {
        int qrow = q0 + QS * 32 + ql;
        int sw = (qrow >> 1) & 3;
        short8 qf0 = *reinterpret_cast<const short8*>(Kbuf + qrow * 32 + ((0 + h) ^ sw) * 8);
        short8 qf1 = *reinterpret_cast<const short8*>(Kbuf + qrow * 32 + ((2 + h) ^ sw) * 8);
        f32x16 sacc;
        #pragma unroll
        for (int i = 0; i < 16; ++i) sacc[i] = 0.f;
        sacc = __builtin_amdgcn_mfma_f32_32x32x16_bf16(kf0, qf0, sacc, 0, 0, 0);
        sacc = __builtin_amdgcn_mfma_f32_32x32x16_bf16(kf1, qf1, sacc, 0, 0, 0);
        float mx = sacc[0];
        #pragma unroll
        for (int r = 1; r < 16; ++r) mx = fmaxf(mx, sacc[r]);
        mx = fmaxf(mx, __shfl_xor(mx, 32));
        float nm = fmaxf(M, mx);
        float fs = __expf(M - nm);
        M = nm;
        float p[16];
        float ps = 0.f;
        #pragma unroll
        for (int r = 0; r < 16; ++r) { p[r] = __expf(sacc[r] - nm); ps += p[r]; }
        ps += __shfl_xor(ps, 32);
        SU = SU * fs + ps;
        u32 P[8];
        #pragma unroll
        for (int g = 0; g < 4; ++g) {
            P[2 * g]     = pk2(p[4 * g],     p[4 * g + 1]);
            P[2 * g + 1] = pk2(p[4 * g + 2], p[4 * g + 3]);
        }
        u32 X[8];
        #pragma unroll
        for (int i = 0; i < 8; ++i) X[i] = __shfl_xor(P[i], 32);
        union { u32 u[4]; short8 s; } c0, c1;
        c0.u[0] = h ? X[2] : P[0];  c0.u[1] = h ? X[3] : P[1];
        c0.u[2] = h ? P[2] : X[0];  c0.u[3] = h ? P[3] : X[1];
        c1.u[0] = h ? X[6] : P[4];  c1.u[1] = h ? X[7] : P[5];
        c1.u[2] = h ? P[6] : X[4];  c1.u[3] = h ? P[7] : X[5];
        #pragma unroll
        for (int r = 0; r < 16; ++r) O[r] *= fs;
        O = __builtin_amdgcn_mfma_f32_32x32x16_bf16(vf0, c0.s, O, 0, 0, 0);
        O = __builtin_amdgcn_mfma_f32_32x32x16_bf16(vf1, c1.s, O, 0, 0, 0);
    };

    for (int kt = 0; kt < 16; ++kt) {
        int k0 = kt * 32;
        int krow = k0 + ql;
        int ksw = (krow >> 1) & 3;
        short8 kf0 = *reinterpret_cast<const short8*>(Kbuf + krow * 32 + ((0 + h) ^ ksw) * 8);
        short8 kf1 = *reinterpret_cast<const short8*>(Kbuf + krow * 32 + ((2 + h) ^ ksw) * 8);
        int ko0 = k0 + h * 8;
        int ko1 = k0 + 16 + h * 8;
        short8 vf0 = *reinterpret_cast<const short8*>(Vt + ql * 512 + ((ko0 >> 3) ^ (ql & 7)) * 8);
        short8 vf1 = *reinterpret_cast<const short8*>(Vt + ql * 512 + ((ko1 >> 3) ^ (ql & 7)) * 8);
        process(0, O0, m0, su0, kf0, kf1, vf0, vf1);
        process(1, O1, m1, su1, kf0, kf1, vf0, vf1);
    }

    // epilogue: normalize + fused LePE from LDS, write bf16.
    // lane's O reg r -> channel d = (r&3) + 8*(r>>2) + 4h (within head)
    #pragma unroll
    for (int QS = 0; QS < 2; ++QS) {
        f32x16& O = QS ? O1 : O0;
        float inv = 1.f / (QS ? su1 : su0);
        int qrow = q0 + QS * 32 + ql;
        int hs  = (br == 0) ? (qrow >> 3) : (qrow >> 6);
        int wsx = (br == 0) ? (qrow & 7)  : (qrow & 63);

        float lep[16];
        #pragma unroll
        for (int r = 0; r < 16; ++r) {
            int d = (r & 3) + 8 * (r >> 2) + 4 * h;
            lep[r] = gbl[d];
        }
        #pragma unroll
        for (int dy = -1; dy <= 1; ++dy) {
            int hn = hs + dy;
            bool okh = (br == 0) ? ((unsigned)hn < 64u) : ((unsigned)hn < 8u);
            #pragma unroll
            for (int dx = -1; dx <= 1; ++dx) {
                int wn = wsx + dx;
                bool okw = (br == 0) ? ((unsigned)wn < 8u) : ((unsigned)wn < 64u);
                if (okh && okw) {
                    int key = (br == 0) ? (hn * 8 + wn) : (hn * 64 + wn);
                    int t = (dy + 1) * 3 + (dx + 1);
                    #pragma unroll
                    for (int r = 0; r < 16; ++r) {
                        int d = (r & 3) + 8 * (r >> 2) + 4 * h;
                        float vv = bf2f((u32)(unsigned short)
                            Vt[d * 512 + (((key >> 3) ^ (d & 7)) * 8 + (key & 7))]);
                        lep[r] += vv * gwl[d * 9 + t];
                    }
                }
            }
        }

        int l = (br == 0) ? ((qrow >> 3) * 64 + wi * 8 + (qrow & 7)) : (wi * 512 + qrow);
        unsigned short* orow = att + ((size_t)(bb * 4096 + l)) * 256 + qk_off;
        #pragma unroll
        for (int g = 0; g < 4; ++g) {
            u32 lo = pk2(O[4 * g] * inv + lep[4 * g],
                         O[4 * g + 1] * inv + lep[4 * g + 1]);
            u32 hi = pk2(O[4 * g + 2] * inv + lep[4 * g + 2],
                         O[4 * g + 3] * inv + lep[4 * g + 3]);
            *reinterpret_cast<uint2*>(orow + 8 * g + 4 * h) = make_uint2(lo, hi);
        }
    }
}

// ---------------------------------------------------------------------------
extern "C" void kernel_launch(void* const* d_in, const int* in_sizes, int n_in,
                              void* d_out, int out_size, void* d_ws, size_t ws_size,
                              hipStream_t stream) {
    const float* x     = (const float*)d_in[0];
    const float* n1w   = (const float*)d_in[1];
    const float* n1b   = (const float*)d_in[2];
    const float* qkvw  = (const float*)d_in[3];
    const float* gw0   = (const float*)d_in[4];
    const float* gb0   = (const float*)d_in[5];
    const float* gw1   = (const float*)d_in[6];
    const float* gb1   = (const float*)d_in[7];
    const float* projw = (const float*)d_in[8];
    const float* projb = (const float*)d_in[9];
    const float* n2w   = (const float*)d_in[10];
    const float* n2b   = (const float*)d_in[11];
    const float* fc1w  = (const float*)d_in[12];
    const float* fc1b  = (const float*)d_in[13];
    const float* fc2w  = (const float*)d_in[14];
    const float* fc2b  = (const float*)d_in[15];
    float* out = (float*)d_out;
    char* wsb  = (char*)d_ws;

    // workspace layout (bytes)
    float*          xT   = (float*)wsb;                          // 16,777,216
    unsigned short* qkv  = (unsigned short*)(wsb + 16777216);    // 16,777,216
    unsigned short* att  = (unsigned short*)(wsb + 33554432);    //  8,388,608
    unsigned short* img  = (unsigned short*)(wsb + 41943040);    //  8,388,608
    unsigned short* wq   = (unsigned short*)(wsb + 50331648);    //    262,144
    unsigned short* wp   = (unsigned short*)(wsb + 50593792);    //    131,072
    unsigned short* w1   = (unsigned short*)(wsb + 50724864);    //    524,288
    unsigned short* w2   = (unsigned short*)(wsb + 51249152);    //    524,288
    unsigned short* ynorm  = img;                                // reuse
    unsigned short* hidden = (unsigned short*)wsb;               // overlays xT+qkv (dead by fc1)

    // weight fp32 -> bf16
    cvt_kernel<<<(131072/4 + 255)/256, 256, 0, stream>>>(qkvw, wq, 131072/4);
    cvt_kernel<<<( 65536/4 + 255)/256, 256, 0, stream>>>(projw, wp,  65536/4);
    cvt_kernel<<<(262144/4 + 255)/256, 256, 0, stream>>>(fc1w,  w1, 262144/4);
    cvt_kernel<<<(262144/4 + 255)/256, 256, 0, stream>>>(fc2w,  w2, 262144/4);

    // norm1 (+ raw fp32 transpose for residual), bf16 out
    norm_kernel<<<4096, 256, 0, stream>>>(x, n1w, n1b, img, xT, 1);
    // qkv = img @ qkv_w^T -> bf16 (16384 x 512)
    mfma_gemm<<<dim3(4, 128), 256, 0, stream>>>(img, wq, nullptr, nullptr, qkv, 512, 256, 1);
    // MFMA windowed attention + fused LePE -> bf16 att
    attn_kernel<<<256, 512, 0, stream>>>(qkv, gw0, gb0, gw1, gb1, att);
    // out = xT + att @ proj_w^T + proj_b (fp32)
    mfma_gemm<<<dim3(2, 128), 256, 0, stream>>>(att, wp, projb, xT, out, 256, 256, 3);
    // norm2 -> bf16
    norm_kernel<<<4096, 256, 0, stream>>>(out, n2w, n2b, ynorm, nullptr, 0);
    // fc1: gelu -> bf16 hidden (16384 x 1024)
    mfma_gemm<<<dim3(8, 128), 256, 0, stream>>>(ynorm, w1, fc1b, nullptr, hidden, 1024, 256, 2);
    // fc2: + bias + resid(out) -> out (16384 x 256)
    mfma_gemm<<<dim3(2, 128), 256, 0, stream>>>(hidden, w2, fc2b, out, out, 256, 1024, 3);
}

// Round 7
// 217.082 us; speedup vs baseline: 5.4817x; 1.0505x over previous
//
#include <hip/hip_runtime.h>
#include <hip/hip_bf16.h>

// Problem geometry (fixed)
#define BDIM 4
#define CDIM 256
#define HDIM 64
#define WDIM 64
#define LDIM 4096   // H*W
#define ROWS 16384  // B*L

typedef __attribute__((ext_vector_type(8))) short short8;
typedef __attribute__((ext_vector_type(4))) float f32x4;
typedef __attribute__((ext_vector_type(16))) float f32x16;
typedef unsigned int u32;

static __device__ __forceinline__ unsigned short f2bf(float f) {
    unsigned int x = __float_as_uint(f);
    unsigned int r = (x + 0x7fffu + ((x >> 16) & 1u)) >> 16;   // RNE
    return (unsigned short)r;
}
static __device__ __forceinline__ float bf2f(unsigned int u) {
    return __uint_as_float(u << 16);
}
static __device__ __forceinline__ u32 pk2(float a, float b) {
    return (u32)f2bf(a) | ((u32)f2bf(b) << 16);
}

// ---------------------------------------------------------------------------
// fp32 -> bf16 conversion of all four weight matrices in ONE launch.
// ranges (in float4 units): qkvw 32768 | projw 16384 | fc1w 65536 | fc2w 65536
// ---------------------------------------------------------------------------
__global__ __launch_bounds__(256) void cvt4_kernel(
    const float* __restrict__ a, const float* __restrict__ b,
    const float* __restrict__ c, const float* __restrict__ d,
    unsigned short* __restrict__ oa, unsigned short* __restrict__ ob,
    unsigned short* __restrict__ oc, unsigned short* __restrict__ od)
{
    int i = blockIdx.x * 256 + threadIdx.x;
    const float* in; unsigned short* out; int off;
    if (i < 32768)       { in = a; out = oa; off = i; }
    else if (i < 49152)  { in = b; out = ob; off = i - 32768; }
    else if (i < 114688) { in = c; out = oc; off = i - 49152; }
    else if (i < 180224) { in = d; out = od; off = i - 114688; }
    else return;
    float4 f = reinterpret_cast<const float4*>(in)[off];
    reinterpret_cast<uint2*>(out)[off] = make_uint2(pk2(f.x, f.y), pk2(f.z, f.w));
}

// ---------------------------------------------------------------------------
// LayerNorm over C=256 -> bf16 out (+ optional raw fp32 transpose copy xT).
// ---------------------------------------------------------------------------
__global__ __launch_bounds__(256) void norm_kernel(
    const float* __restrict__ xin,
    const float* __restrict__ w, const float* __restrict__ b,
    unsigned short* __restrict__ out,
    float* __restrict__ xT,
    int transposed_in)
{
    int wave = threadIdx.x >> 6;
    int lane = threadIdx.x & 63;
    int row = blockIdx.x * 4 + wave;
    float v[4];
    float sum = 0.f, sumsq = 0.f;
    if (transposed_in) {
        int bb = row >> 12;
        int l = row & 4095;
        const float* xb = xin + (size_t)bb * (CDIM * LDIM) + l;
        #pragma unroll
        for (int i = 0; i < 4; ++i) {
            int c = lane + i * 64;
            float t = xb[(size_t)c * LDIM];
            v[i] = t; sum += t; sumsq += t * t;
        }
    } else {
        const float* xr = xin + (size_t)row * CDIM;
        #pragma unroll
        for (int i = 0; i < 4; ++i) {
            float t = xr[lane + i * 64];
            v[i] = t; sum += t; sumsq += t * t;
        }
    }
    #pragma unroll
    for (int off = 32; off > 0; off >>= 1) {
        sum   += __shfl_xor(sum, off);
        sumsq += __shfl_xor(sumsq, off);
    }
    float mean = sum * (1.f / 256.f);
    float var  = sumsq * (1.f / 256.f) - mean * mean;
    float inv  = rsqrtf(var + 1e-5f);
    unsigned short* orow = out + (size_t)row * CDIM;
    #pragma unroll
    for (int i = 0; i < 4; ++i) {
        int c = lane + i * 64;
        if (xT) xT[(size_t)row * CDIM + c] = v[i];
        orow[c] = f2bf((v[i] - mean) * inv * w[c] + b[c]);
    }
}

// ---------------------------------------------------------------------------
// bf16 MFMA GEMM: C = A @ B^T (+ bias / gelu / resid), fp32 accumulate.
// 128x128 tile, BK=32, 4 waves, 16x16x32 frags. Double-buffered 2-phase
// pipeline (T3-minimum): stage tile t+1 before computing tile t; single
// __syncthreads per K-step (its implicit vmcnt/lgkm drain covers the flip).
// global_load_lds staging with both-sides XOR swizzle.
// mode: 0 plain->f32; 1 plain->bf16; 2 +bias,gelu->bf16; 3 +bias+resid->f32
// ---------------------------------------------------------------------------
__global__ __launch_bounds__(256) void mfma_gemm(
    const unsigned short* __restrict__ A,
    const unsigned short* __restrict__ Bm,
    const float* __restrict__ bias,
    const float* __restrict__ resid,
    void* __restrict__ outp,
    int N, int K, int mode)
{
    __shared__ unsigned short As[2][128 * 32];
    __shared__ unsigned short Bs[2][128 * 32];
    int tid  = threadIdx.x;
    int lane = tid & 63;
    int w    = tid >> 6;
    int wr   = w >> 1, wc = w & 1;
    int l15  = lane & 15, kbl = lane >> 4;
    int n0 = blockIdx.x * 128, m0 = blockIdx.y * 128;

    f32x4 acc[4][4];
    #pragma unroll
    for (int m = 0; m < 4; ++m)
        #pragma unroll
        for (int n = 0; n < 4; ++n)
            acc[m][n] = (f32x4){0.f, 0.f, 0.f, 0.f};

    int kbr = kbl ^ (l15 & 3);

    // per-thread staging coords (fixed across K-steps)
    int c0r = (tid * 2) >> 3,     c0k = (tid * 2) & 7;        // unused form
    // chunk c = i*256+tid, row = c>>2, kbp = c&3, cbg = kbp ^ (row&3)
    auto STAGE = [&](int buf, int k0) {
        #pragma unroll
        for (int i = 0; i < 2; ++i) {
            int c = i * 256 + tid;
            int row = c >> 2, kbp = c & 3;
            int cbg = kbp ^ (row & 3);
            const unsigned short* ga = A  + (size_t)(m0 + row) * K + k0 + cbg * 8;
            const unsigned short* gb = Bm + (size_t)(n0 + row) * K + k0 + cbg * 8;
            __builtin_amdgcn_global_load_lds(
                (const __attribute__((address_space(1))) void*)ga,
                (__attribute__((address_space(3))) void*)(As[buf] + c * 8), 16, 0, 0);
            __builtin_amdgcn_global_load_lds(
                (const __attribute__((address_space(1))) void*)gb,
                (__attribute__((address_space(3))) void*)(Bs[buf] + c * 8), 16, 0, 0);
        }
    };
    (void)c0r; (void)c0k;

    STAGE(0, 0);
    __syncthreads();           // drain vmcnt, publish buf0

    int cur = 0;
    for (int k0 = 0; k0 < K; k0 += 32) {
        if (k0 + 32 < K) STAGE(cur ^ 1, k0 + 32);   // prefetch next tile

        short8 af[4], bf[4];
        #pragma unroll
        for (int m = 0; m < 4; ++m) {
            int row = wr * 64 + m * 16 + l15;
            af[m] = *reinterpret_cast<const short8*>(As[cur] + row * 32 + kbr * 8);
        }
        #pragma unroll
        for (int n = 0; n < 4; ++n) {
            int row = wc * 64 + n * 16 + l15;
            bf[n] = *reinterpret_cast<const short8*>(Bs[cur] + row * 32 + kbr * 8);
        }
        #pragma unroll
        for (int m = 0; m < 4; ++m)
            #pragma unroll
            for (int n = 0; n < 4; ++n)
                acc[m][n] = __builtin_amdgcn_mfma_f32_16x16x32_bf16(
                    af[m], bf[n], acc[m][n], 0, 0, 0);

        __syncthreads();       // drains prefetch vmcnt + guards buffer reuse
        cur ^= 1;
    }

    int r0 = kbl * 4;
    #pragma unroll
    for (int m = 0; m < 4; ++m) {
        #pragma unroll
        for (int n = 0; n < 4; ++n) {
            int col = n0 + wc * 64 + n * 16 + l15;
            #pragma unroll
            for (int r = 0; r < 4; ++r) {
                int row = m0 + wr * 64 + m * 16 + r0 + r;
                float v = acc[m][n][r];
                if (mode == 0) {
                    ((float*)outp)[(size_t)row * N + col] = v;
                } else if (mode == 1) {
                    ((unsigned short*)outp)[(size_t)row * N + col] = f2bf(v);
                } else if (mode == 2) {
                    v += bias[col];
                    v = 0.5f * v * (1.f + erff(v * 0.70710678118654752f));
                    ((unsigned short*)outp)[(size_t)row * N + col] = f2bf(v);
                } else {
                    v += bias[col] + resid[(size_t)row * N + col];
                    ((float*)outp)[(size_t)row * N + col] = v;
                }
            }
        }
    }
}

// ---------------------------------------------------------------------------
// MFMA windowed attention + fused LePE. One block per (window, head): 512 thr.
// Swapped QK^T; online softmax lane-local; P->bf16 + partner shfl; swapped PV.
// K (pre-scaled) and V^T staged in LDS with both-sides XOR slot swizzles.
// LePE 3x3 depthwise computed in the epilogue from the LDS V^T tile.
// ---------------------------------------------------------------------------
__global__ __launch_bounds__(512) void attn_kernel(
    const unsigned short* __restrict__ qkv,   // ROWS x 512 bf16
    const float* __restrict__ gw0, const float* __restrict__ gb0,
    const float* __restrict__ gw1, const float* __restrict__ gb1,
    unsigned short* __restrict__ att)         // ROWS x 256 bf16
{
    __shared__ unsigned short Kbuf[512 * 32]; // [row][d], slot ^= (row>>1)&3
    __shared__ unsigned short Vt[32 * 512];   // [d][key], slot ^= d&7
    __shared__ float gwl[288];                // this head's 32ch x 9 taps
    __shared__ float gbl[32];
    const int wh = blockIdx.x;
    const int br = wh >> 7, head = wh & 3, win = (wh >> 2) & 31;
    const int bb = win >> 3, wi = win & 7;
    const int tid = threadIdx.x;
    const int qk_off = br * 128 + head * 32;
    const int v_off = 256 + qk_off;
    const float sscale = 0.42044820762685725f;  // 32^-0.25 = sqrt(scale)

    // ---- stage LePE weights (head's 32-channel slice) ----
    {
        const float* gw = br ? gw1 : gw0;
        const float* gb = br ? gb1 : gb0;
        if (tid < 288) gwl[tid] = gw[(head * 32) * 9 + tid];
        else if (tid >= 480) gbl[tid - 480] = gb[head * 32 + tid - 480];
    }
    // ---- stage K (scaled) ----
    {
        int t = tid;
        int l = (br == 0) ? ((t >> 3) * 64 + wi * 8 + (t & 7)) : (wi * 512 + t);
        const unsigned short* src = qkv + ((size_t)(bb * 4096 + l)) * 512 + qk_off;
        #pragma unroll
        for (int s = 0; s < 4; ++s) {
            uint4 raw = *reinterpret_cast<const uint4*>(src + s * 8);
            u32 rw[4] = {raw.x, raw.y, raw.z, raw.w};
            u32 ow[4];
            #pragma unroll
            for (int i = 0; i < 4; ++i) {
                float lo = bf2f(rw[i] & 0xffffu) * sscale;
                float hi = bf2f(rw[i] >> 16) * sscale;
                ow[i] = pk2(lo, hi);
            }
            int sl = s ^ ((t >> 1) & 3);
            *reinterpret_cast<uint4*>(Kbuf + t * 32 + sl * 8) =
                make_uint4(ow[0], ow[1], ow[2], ow[3]);
        }
    }
    // ---- stage V transposed ----
    {
        int kp = (tid & 255) * 2, dh = tid >> 8;
        int kq = kp + 1;
        int l0 = (br == 0) ? ((kp >> 3) * 64 + wi * 8 + (kp & 7)) : (wi * 512 + kp);
        int l1 = (br == 0) ? ((kq >> 3) * 64 + wi * 8 + (kq & 7)) : (wi * 512 + kq);
        const unsigned short* v0 = qkv + ((size_t)(bb * 4096 + l0)) * 512 + v_off + dh * 16;
        const unsigned short* v1 = qkv + ((size_t)(bb * 4096 + l1)) * 512 + v_off + dh * 16;
        uint4 a0 = *reinterpret_cast<const uint4*>(v0);
        uint4 a1 = *reinterpret_cast<const uint4*>(v0 + 8);
        uint4 b0 = *reinterpret_cast<const uint4*>(v1);
        uint4 b1 = *reinterpret_cast<const uint4*>(v1 + 8);
        u32 av[8] = {a0.x, a0.y, a0.z, a0.w, a1.x, a1.y, a1.z, a1.w};
        u32 bv[8] = {b0.x, b0.y, b0.z, b0.w, b1.x, b1.y, b1.z, b1.w};
        int slot = kp >> 3;
        #pragma unroll
        for (int dd = 0; dd < 16; ++dd) {
            u32 x0 = (dd & 1) ? (av[dd >> 1] >> 16) : (av[dd >> 1] & 0xffffu);
            u32 x1 = (dd & 1) ? (bv[dd >> 1] >> 16) : (bv[dd >> 1] & 0xffffu);
            int d = dh * 16 + dd;
            int sl = slot ^ (d & 7);
            *reinterpret_cast<u32*>(Vt + d * 512 + sl * 8 + (kp & 7)) = x0 | (x1 << 16);
        }
    }
    __syncthreads();

    const int lane = tid & 63;
    const int w = tid >> 6;
    const int ql = lane & 31;
    const int h = lane >> 5;
    const int q0 = w * 64;

    f32x16 O0, O1;
    #pragma unroll
    for (int i = 0; i < 16; ++i) { O0[i] = 0.f; O1[i] = 0.f; }
    float m0 = -1e30f, m1 = -1e30f, su0 = 0.f, su1 = 0.f;

    auto process = [&](int QS, f32x16& O, float& M, float& SU,
                       short8 kf0, short8 kf1, short8 vf0, short8 vf1) {
        int qrow = q0 + QS * 32 + ql;
        int sw = (qrow >> 1) & 3;
        short8 qf0 = *reinterpret_cast<const short8*>(Kbuf + qrow * 32 + ((0 + h) ^ sw) * 8);
        short8 qf1 = *reinterpret_cast<const short8*>(Kbuf + qrow * 32 + ((2 + h) ^ sw) * 8);
        f32x16 sacc;
        #pragma unroll
        for (int i = 0; i < 16; ++i) sacc[i] = 0.f;
        sacc = __builtin_amdgcn_mfma_f32_32x32x16_bf16(kf0, qf0, sacc, 0, 0, 0);
        sacc = __builtin_amdgcn_mfma_f32_32x32x16_bf16(kf1, qf1, sacc, 0, 0, 0);
        float mx = sacc[0];
        #pragma unroll
        for (int r = 1; r < 16; ++r) mx = fmaxf(mx, sacc[r]);
        mx = fmaxf(mx, __shfl_xor(mx, 32));
        float nm = fmaxf(M, mx);
        float fs = __expf(M - nm);
        M = nm;
        float p[16];
        float ps = 0.f;
        #pragma unroll
        for (int r = 0; r < 16; ++r) { p[r] = __expf(sacc[r] - nm); ps += p[r]; }
        ps += __shfl_xor(ps, 32);
        SU = SU * fs + ps;
        u32 P[8];
        #pragma unroll
        for (int g = 0; g < 4; ++g) {
            P[2 * g]     = pk2(p[4 * g],     p[4 * g + 1]);
            P[2 * g + 1] = pk2(p[4 * g + 2], p[4 * g + 3]);
        }
        u32 X[8];
        #pragma unroll
        for (int i = 0; i < 8; ++i) X[i] = __shfl_xor(P[i], 32);
        union { u32 u[4]; short8 s; } c0, c1;
        c0.u[0] = h ? X[2] : P[0];  c0.u[1] = h ? X[3] : P[1];
        c0.u[2] = h ? P[2] : X[0];  c0.u[3] = h ? P[3] : X[1];
        c1.u[0] = h ? X[6] : P[4];  c1.u[1] = h ? X[7] : P[5];
        c1.u[2] = h ? P[6] : X[4];  c1.u[3] = h ? P[7] : X[5];
        #pragma unroll
        for (int r = 0; r < 16; ++r) O[r] *= fs;
        O = __builtin_amdgcn_mfma_f32_32x32x16_bf16(vf0, c0.s, O, 0, 0, 0);
        O = __builtin_amdgcn_mfma_f32_32x32x16_bf16(vf1, c1.s, O, 0, 0, 0);
    };

    for (int kt = 0; kt < 16; ++kt) {
        int k0 = kt * 32;
        int krow = k0 + ql;
        int ksw = (krow >> 1) & 3;
        short8 kf0 = *reinterpret_cast<const short8*>(Kbuf + krow * 32 + ((0 + h) ^ ksw) * 8);
        short8 kf1 = *reinterpret_cast<const short8*>(Kbuf + krow * 32 + ((2 + h) ^ ksw) * 8);
        int ko0 = k0 + h * 8;
        int ko1 = k0 + 16 + h * 8;
        short8 vf0 = *reinterpret_cast<const short8*>(Vt + ql * 512 + ((ko0 >> 3) ^ (ql & 7)) * 8);
        short8 vf1 = *reinterpret_cast<const short8*>(Vt + ql * 512 + ((ko1 >> 3) ^ (ql & 7)) * 8);
        process(0, O0, m0, su0, kf0, kf1, vf0, vf1);
        process(1, O1, m1, su1, kf0, kf1, vf0, vf1);
    }

    // epilogue: normalize + fused LePE from LDS, write bf16.
    // lane's O reg r -> channel d = (r&3) + 8*(r>>2) + 4h (within head)
    #pragma unroll
    for (int QS = 0; QS < 2; ++QS) {
        f32x16& O = QS ? O1 : O0;
        float inv = 1.f / (QS ? su1 : su0);
        int qrow = q0 + QS * 32 + ql;
        int hs  = (br == 0) ? (qrow >> 3) : (qrow >> 6);
        int wsx = (br == 0) ? (qrow & 7)  : (qrow & 63);

        float lep[16];
        #pragma unroll
        for (int r = 0; r < 16; ++r) {
            int d = (r & 3) + 8 * (r >> 2) + 4 * h;
            lep[r] = gbl[d];
        }
        #pragma unroll
        for (int dy = -1; dy <= 1; ++dy) {
            int hn = hs + dy;
            bool okh = (br == 0) ? ((unsigned)hn < 64u) : ((unsigned)hn < 8u);
            #pragma unroll
            for (int dx = -1; dx <= 1; ++dx) {
                int wn = wsx + dx;
                bool okw = (br == 0) ? ((unsigned)wn < 8u) : ((unsigned)wn < 64u);
                if (okh && okw) {
                    int key = (br == 0) ? (hn * 8 + wn) : (hn * 64 + wn);
                    int t = (dy + 1) * 3 + (dx + 1);
                    #pragma unroll
                    for (int r = 0; r < 16; ++r) {
                        int d = (r & 3) + 8 * (r >> 2) + 4 * h;
                        float vv = bf2f((u32)(unsigned short)
                            Vt[d * 512 + (((key >> 3) ^ (d & 7)) * 8 + (key & 7))]);
                        lep[r] += vv * gwl[d * 9 + t];
                    }
                }
            }
        }

        int l = (br == 0) ? ((qrow >> 3) * 64 + wi * 8 + (qrow & 7)) : (wi * 512 + qrow);
        unsigned short* orow = att + ((size_t)(bb * 4096 + l)) * 256 + qk_off;
        #pragma unroll
        for (int g = 0; g < 4; ++g) {
            u32 lo = pk2(O[4 * g] * inv + lep[4 * g],
                         O[4 * g + 1] * inv + lep[4 * g + 1]);
            u32 hi = pk2(O[4 * g + 2] * inv + lep[4 * g + 2],
                         O[4 * g + 3] * inv + lep[4 * g + 3]);
            *reinterpret_cast<uint2*>(orow + 8 * g + 4 * h) = make_uint2(lo, hi);
        }
    }
}

// ---------------------------------------------------------------------------
extern "C" void kernel_launch(void* const* d_in, const int* in_sizes, int n_in,
                              void* d_out, int out_size, void* d_ws, size_t ws_size,
                              hipStream_t stream) {
    const float* x     = (const float*)d_in[0];
    const float* n1w   = (const float*)d_in[1];
    const float* n1b   = (const float*)d_in[2];
    const float* qkvw  = (const float*)d_in[3];
    const float* gw0   = (const float*)d_in[4];
    const float* gb0   = (const float*)d_in[5];
    const float* gw1   = (const float*)d_in[6];
    const float* gb1   = (const float*)d_in[7];
    const float* projw = (const float*)d_in[8];
    const float* projb = (const float*)d_in[9];
    const float* n2w   = (const float*)d_in[10];
    const float* n2b   = (const float*)d_in[11];
    const float* fc1w  = (const float*)d_in[12];
    const float* fc1b  = (const float*)d_in[13];
    const float* fc2w  = (const float*)d_in[14];
    const float* fc2b  = (const float*)d_in[15];
    float* out = (float*)d_out;
    char* wsb  = (char*)d_ws;

    // workspace layout (bytes)
    float*          xT   = (float*)wsb;                          // 16,777,216
    unsigned short* qkv  = (unsigned short*)(wsb + 16777216);    // 16,777,216
    unsigned short* att  = (unsigned short*)(wsb + 33554432);    //  8,388,608
    unsigned short* img  = (unsigned short*)(wsb + 41943040);    //  8,388,608
    unsigned short* wq   = (unsigned short*)(wsb + 50331648);    //    262,144
    unsigned short* wp   = (unsigned short*)(wsb + 50593792);    //    131,072
    unsigned short* w1   = (unsigned short*)(wsb + 50724864);    //    524,288
    unsigned short* w2   = (unsigned short*)(wsb + 51249152);    //    524,288
    unsigned short* ynorm  = img;                                // reuse
    unsigned short* hidden = (unsigned short*)wsb;               // overlays xT+qkv (dead by fc1)

    // weight fp32 -> bf16 (one launch)
    cvt4_kernel<<<704, 256, 0, stream>>>(qkvw, projw, fc1w, fc2w, wq, wp, w1, w2);

    // norm1 (+ raw fp32 transpose for residual), bf16 out
    norm_kernel<<<4096, 256, 0, stream>>>(x, n1w, n1b, img, xT, 1);
    // qkv = img @ qkv_w^T -> bf16 (16384 x 512)
    mfma_gemm<<<dim3(4, 128), 256, 0, stream>>>(img, wq, nullptr, nullptr, qkv, 512, 256, 1);
    // MFMA windowed attention + fused LePE -> bf16 att
    attn_kernel<<<256, 512, 0, stream>>>(qkv, gw0, gb0, gw1, gb1, att);
    // out = xT + att @ proj_w^T + proj_b (fp32)
    mfma_gemm<<<dim3(2, 128), 256, 0, stream>>>(att, wp, projb, xT, out, 256, 256, 3);
    // norm2 -> bf16
    norm_kernel<<<4096, 256, 0, stream>>>(out, n2w, n2b, ynorm, nullptr, 0);
    // fc1: gelu -> bf16 hidden (16384 x 1024)
    mfma_gemm<<<dim3(8, 128), 256, 0, stream>>>(ynorm, w1, fc1b, nullptr, hidden, 1024, 256, 2);
    // fc2: + bias + resid(out) -> out (16384 x 256)
    mfma_gemm<<<dim3(2, 128), 256, 0, stream>>>(hidden, w2, fc2b, out, out, 256, 1024, 3);
}

// Round 8
// 162.361 us; speedup vs baseline: 7.3292x; 1.3370x over previous
//
#include <hip/hip_runtime.h>
#include <hip/hip_bf16.h>

// Problem geometry (fixed)
#define BDIM 4
#define CDIM 256
#define HDIM 64
#define WDIM 64
#define LDIM 4096   // H*W
#define ROWS 16384  // B*L

typedef __attribute__((ext_vector_type(8))) short short8;
typedef __attribute__((ext_vector_type(4))) float f32x4;
typedef __attribute__((ext_vector_type(16))) float f32x16;
typedef unsigned int u32;

static __device__ __forceinline__ unsigned short f2bf(float f) {
    unsigned int x = __float_as_uint(f);
    unsigned int r = (x + 0x7fffu + ((x >> 16) & 1u)) >> 16;   // RNE
    return (unsigned short)r;
}
static __device__ __forceinline__ float bf2f(unsigned int u) {
    return __uint_as_float(u << 16);
}
static __device__ __forceinline__ u32 pk2(float a, float b) {
    return (u32)f2bf(a) | ((u32)f2bf(b) << 16);
}

// ---------------------------------------------------------------------------
// fp32 -> bf16 conversion of all four weight matrices in ONE launch.
// ranges (in float4 units): qkvw 32768 | projw 16384 | fc1w 65536 | fc2w 65536
// ---------------------------------------------------------------------------
__global__ __launch_bounds__(256) void cvt4_kernel(
    const float* __restrict__ a, const float* __restrict__ b,
    const float* __restrict__ c, const float* __restrict__ d,
    unsigned short* __restrict__ oa, unsigned short* __restrict__ ob,
    unsigned short* __restrict__ oc, unsigned short* __restrict__ od)
{
    int i = blockIdx.x * 256 + threadIdx.x;
    const float* in; unsigned short* out; int off;
    if (i < 32768)       { in = a; out = oa; off = i; }
    else if (i < 49152)  { in = b; out = ob; off = i - 32768; }
    else if (i < 114688) { in = c; out = oc; off = i - 49152; }
    else if (i < 180224) { in = d; out = od; off = i - 114688; }
    else return;
    float4 f = reinterpret_cast<const float4*>(in)[off];
    reinterpret_cast<uint2*>(out)[off] = make_uint2(pk2(f.x, f.y), pk2(f.z, f.w));
}

// ---------------------------------------------------------------------------
// LayerNorm over C=256 -> bf16 out (+ optional raw fp32 transpose copy xT).
// ---------------------------------------------------------------------------
__global__ __launch_bounds__(256) void norm_kernel(
    const float* __restrict__ xin,
    const float* __restrict__ w, const float* __restrict__ b,
    unsigned short* __restrict__ out,
    float* __restrict__ xT,
    int transposed_in)
{
    int wave = threadIdx.x >> 6;
    int lane = threadIdx.x & 63;
    int row = blockIdx.x * 4 + wave;
    float v[4];
    float sum = 0.f, sumsq = 0.f;
    if (transposed_in) {
        int bb = row >> 12;
        int l = row & 4095;
        const float* xb = xin + (size_t)bb * (CDIM * LDIM) + l;
        #pragma unroll
        for (int i = 0; i < 4; ++i) {
            int c = lane + i * 64;
            float t = xb[(size_t)c * LDIM];
            v[i] = t; sum += t; sumsq += t * t;
        }
    } else {
        const float* xr = xin + (size_t)row * CDIM;
        #pragma unroll
        for (int i = 0; i < 4; ++i) {
            float t = xr[lane + i * 64];
            v[i] = t; sum += t; sumsq += t * t;
        }
    }
    #pragma unroll
    for (int off = 32; off > 0; off >>= 1) {
        sum   += __shfl_xor(sum, off);
        sumsq += __shfl_xor(sumsq, off);
    }
    float mean = sum * (1.f / 256.f);
    float var  = sumsq * (1.f / 256.f) - mean * mean;
    float inv  = rsqrtf(var + 1e-5f);
    unsigned short* orow = out + (size_t)row * CDIM;
    #pragma unroll
    for (int i = 0; i < 4; ++i) {
        int c = lane + i * 64;
        if (xT) xT[(size_t)row * CDIM + c] = v[i];
        orow[c] = f2bf((v[i] - mean) * inv * w[c] + b[c]);
    }
}

// ---------------------------------------------------------------------------
// bf16 MFMA GEMM: C = A @ B^T (+ bias / gelu / resid), fp32 accumulate.
// 64x64 tile, BK=32, 256 thr = 4 waves (2x2), each wave 2x2 16x16x32 frags.
// Small tile => 1024-4096 blocks => 4-8 blocks/CU resident (TLP latency
// hiding for the skinny K=256 shapes). Double-buffered staging via
// global_load_lds(16B), both-sides XOR slot swizzle (slot ^= row&3).
// Bijective XCD-chunk swizzle on the block id (all grids % 8 == 0).
// mode: 0 plain->f32; 1 plain->bf16; 2 +bias,gelu->bf16; 3 +bias+resid->f32
// ---------------------------------------------------------------------------
__global__ __launch_bounds__(256) void mfma_gemm(
    const unsigned short* __restrict__ A,
    const unsigned short* __restrict__ Bm,
    const float* __restrict__ bias,
    const float* __restrict__ resid,
    void* __restrict__ outp,
    int N, int K, int mode)
{
    __shared__ unsigned short As[2][64 * 32];
    __shared__ unsigned short Bs[2][64 * 32];
    int tid  = threadIdx.x;
    int lane = tid & 63;
    int w    = tid >> 6;
    int wr   = w >> 1, wc = w & 1;
    int l15  = lane & 15, kbl = lane >> 4;

    // XCD-aware bijective chunk swizzle (nwg % 8 == 0 for all our grids)
    int gx  = gridDim.x;
    int nwg = gx * gridDim.y;
    int bid = blockIdx.y * gx + blockIdx.x;
    int cpx = nwg >> 3;
    int swz = (bid & 7) * cpx + (bid >> 3);
    int n0 = (swz % gx) * 64;
    int m0 = (swz / gx) * 64;

    f32x4 acc[2][2];
    #pragma unroll
    for (int m = 0; m < 2; ++m)
        #pragma unroll
        for (int n = 0; n < 2; ++n)
            acc[m][n] = (f32x4){0.f, 0.f, 0.f, 0.f};

    // staging coords: 256 chunks of 16B per matrix, 1 per thread
    int srow = tid >> 2;        // 0..63
    int sp   = tid & 3;         // physical slot
    int ss   = sp ^ (srow & 3); // logical slot -> global col block
    auto STAGE = [&](int buf, int k0) {
        const unsigned short* ga = A  + (size_t)(m0 + srow) * K + k0 + ss * 8;
        const unsigned short* gb = Bm + (size_t)(n0 + srow) * K + k0 + ss * 8;
        __builtin_amdgcn_global_load_lds(
            (const __attribute__((address_space(1))) void*)ga,
            (__attribute__((address_space(3))) void*)(As[buf] + tid * 8), 16, 0, 0);
        __builtin_amdgcn_global_load_lds(
            (const __attribute__((address_space(1))) void*)gb,
            (__attribute__((address_space(3))) void*)(Bs[buf] + tid * 8), 16, 0, 0);
    };

    STAGE(0, 0);
    __syncthreads();

    int cur = 0;
    for (int k0 = 0; k0 < K; k0 += 32) {
        if (k0 + 32 < K) STAGE(cur ^ 1, k0 + 32);

        short8 af[2], bf[2];
        #pragma unroll
        for (int m = 0; m < 2; ++m) {
            int row = wr * 32 + m * 16 + l15;
            af[m] = *reinterpret_cast<const short8*>(
                As[cur] + row * 32 + (kbl ^ (row & 3)) * 8);
        }
        #pragma unroll
        for (int n = 0; n < 2; ++n) {
            int row = wc * 32 + n * 16 + l15;
            bf[n] = *reinterpret_cast<const short8*>(
                Bs[cur] + row * 32 + (kbl ^ (row & 3)) * 8);
        }
        #pragma unroll
        for (int m = 0; m < 2; ++m)
            #pragma unroll
            for (int n = 0; n < 2; ++n)
                acc[m][n] = __builtin_amdgcn_mfma_f32_16x16x32_bf16(
                    af[m], bf[n], acc[m][n], 0, 0, 0);

        __syncthreads();
        cur ^= 1;
    }

    // epilogue: C/D mapping col = lane&15, row = (lane>>4)*4 + reg
    int r0 = kbl * 4;
    #pragma unroll
    for (int m = 0; m < 2; ++m) {
        #pragma unroll
        for (int n = 0; n < 2; ++n) {
            int col = n0 + wc * 32 + n * 16 + l15;
            #pragma unroll
            for (int r = 0; r < 4; ++r) {
                int row = m0 + wr * 32 + m * 16 + r0 + r;
                float v = acc[m][n][r];
                if (mode == 0) {
                    ((float*)outp)[(size_t)row * N + col] = v;
                } else if (mode == 1) {
                    ((unsigned short*)outp)[(size_t)row * N + col] = f2bf(v);
                } else if (mode == 2) {
                    v += bias[col];
                    v = 0.5f * v * (1.f + erff(v * 0.70710678118654752f));
                    ((unsigned short*)outp)[(size_t)row * N + col] = f2bf(v);
                } else {
                    v += bias[col] + resid[(size_t)row * N + col];
                    ((float*)outp)[(size_t)row * N + col] = v;
                }
            }
        }
    }
}

// ---------------------------------------------------------------------------
// MFMA windowed attention + fused LePE. One block per (window, head): 512 thr.
// Swapped QK^T; online softmax lane-local; P->bf16 + partner shfl; swapped PV.
// K (pre-scaled) and V^T staged in LDS with both-sides XOR slot swizzles.
// LePE 3x3 depthwise computed in the epilogue from the LDS V^T tile.
// ---------------------------------------------------------------------------
__global__ __launch_bounds__(512) void attn_kernel(
    const unsigned short* __restrict__ qkv,   // ROWS x 512 bf16
    const float* __restrict__ gw0, const float* __restrict__ gb0,
    const float* __restrict__ gw1, const float* __restrict__ gb1,
    unsigned short* __restrict__ att)         // ROWS x 256 bf16
{
    __shared__ unsigned short Kbuf[512 * 32]; // [row][d], slot ^= (row>>1)&3
    __shared__ unsigned short Vt[32 * 512];   // [d][key], slot ^= d&7
    __shared__ float gwl[288];                // this head's 32ch x 9 taps
    __shared__ float gbl[32];
    const int wh = blockIdx.x;
    const int br = wh >> 7, head = wh & 3, win = (wh >> 2) & 31;
    const int bb = win >> 3, wi = win & 7;
    const int tid = threadIdx.x;
    const int qk_off = br * 128 + head * 32;
    const int v_off = 256 + qk_off;
    const float sscale = 0.42044820762685725f;  // 32^-0.25 = sqrt(scale)

    // ---- stage LePE weights (head's 32-channel slice) ----
    {
        const float* gw = br ? gw1 : gw0;
        const float* gb = br ? gb1 : gb0;
        if (tid < 288) gwl[tid] = gw[(head * 32) * 9 + tid];
        else if (tid >= 480) gbl[tid - 480] = gb[head * 32 + tid - 480];
    }
    // ---- stage K (scaled) ----
    {
        int t = tid;
        int l = (br == 0) ? ((t >> 3) * 64 + wi * 8 + (t & 7)) : (wi * 512 + t);
        const unsigned short* src = qkv + ((size_t)(bb * 4096 + l)) * 512 + qk_off;
        #pragma unroll
        for (int s = 0; s < 4; ++s) {
            uint4 raw = *reinterpret_cast<const uint4*>(src + s * 8);
            u32 rw[4] = {raw.x, raw.y, raw.z, raw.w};
            u32 ow[4];
            #pragma unroll
            for (int i = 0; i < 4; ++i) {
                float lo = bf2f(rw[i] & 0xffffu) * sscale;
                float hi = bf2f(rw[i] >> 16) * sscale;
                ow[i] = pk2(lo, hi);
            }
            int sl = s ^ ((t >> 1) & 3);
            *reinterpret_cast<uint4*>(Kbuf + t * 32 + sl * 8) =
                make_uint4(ow[0], ow[1], ow[2], ow[3]);
        }
    }
    // ---- stage V transposed ----
    {
        int kp = (tid & 255) * 2, dh = tid >> 8;
        int kq = kp + 1;
        int l0 = (br == 0) ? ((kp >> 3) * 64 + wi * 8 + (kp & 7)) : (wi * 512 + kp);
        int l1 = (br == 0) ? ((kq >> 3) * 64 + wi * 8 + (kq & 7)) : (wi * 512 + kq);
        const unsigned short* v0 = qkv + ((size_t)(bb * 4096 + l0)) * 512 + v_off + dh * 16;
        const unsigned short* v1 = qkv + ((size_t)(bb * 4096 + l1)) * 512 + v_off + dh * 16;
        uint4 a0 = *reinterpret_cast<const uint4*>(v0);
        uint4 a1 = *reinterpret_cast<const uint4*>(v0 + 8);
        uint4 b0 = *reinterpret_cast<const uint4*>(v1);
        uint4 b1 = *reinterpret_cast<const uint4*>(v1 + 8);
        u32 av[8] = {a0.x, a0.y, a0.z, a0.w, a1.x, a1.y, a1.z, a1.w};
        u32 bv[8] = {b0.x, b0.y, b0.z, b0.w, b1.x, b1.y, b1.z, b1.w};
        int slot = kp >> 3;
        #pragma unroll
        for (int dd = 0; dd < 16; ++dd) {
            u32 x0 = (dd & 1) ? (av[dd >> 1] >> 16) : (av[dd >> 1] & 0xffffu);
            u32 x1 = (dd & 1) ? (bv[dd >> 1] >> 16) : (bv[dd >> 1] & 0xffffu);
            int d = dh * 16 + dd;
            int sl = slot ^ (d & 7);
            *reinterpret_cast<u32*>(Vt + d * 512 + sl * 8 + (kp & 7)) = x0 | (x1 << 16);
        }
    }
    __syncthreads();

    const int lane = tid & 63;
    const int w = tid >> 6;
    const int ql = lane & 31;
    const int h = lane >> 5;
    const int q0 = w * 64;

    f32x16 O0, O1;
    #pragma unroll
    for (int i = 0; i < 16; ++i) { O0[i] = 0.f; O1[i] = 0.f; }
    float m0 = -1e30f, m1 = -1e30f, su0 = 0.f, su1 = 0.f;

    auto process = [&](int QS, f32x16& O, float& M, float& SU,
                       short8 kf0, short8 kf1, short8 vf0, short8 vf1) {
        int qrow = q0 + QS * 32 + ql;
        int sw = (qrow >> 1) & 3;
        short8 qf0 = *reinterpret_cast<const short8*>(Kbuf + qrow * 32 + ((0 + h) ^ sw) * 8);
        short8 qf1 = *reinterpret_cast<const short8*>(Kbuf + qrow * 32 + ((2 + h) ^ sw) * 8);
        f32x16 sacc;
        #pragma unroll
        for (int i = 0; i < 16; ++i) sacc[i] = 0.f;
        sacc = __builtin_amdgcn_mfma_f32_32x32x16_bf16(kf0, qf0, sacc, 0, 0, 0);
        sacc = __builtin_amdgcn_mfma_f32_32x32x16_bf16(kf1, qf1, sacc, 0, 0, 0);
        float mx = sacc[0];
        #pragma unroll
        for (int r = 1; r < 16; ++r) mx = fmaxf(mx, sacc[r]);
        mx = fmaxf(mx, __shfl_xor(mx, 32));
        float nm = fmaxf(M, mx);
        float fs = __expf(M - nm);
        M = nm;
        float p[16];
        float ps = 0.f;
        #pragma unroll
        for (int r = 0; r < 16; ++r) { p[r] = __expf(sacc[r] - nm); ps += p[r]; }
        ps += __shfl_xor(ps, 32);
        SU = SU * fs + ps;
        u32 P[8];
        #pragma unroll
        for (int g = 0; g < 4; ++g) {
            P[2 * g]     = pk2(p[4 * g],     p[4 * g + 1]);
            P[2 * g + 1] = pk2(p[4 * g + 2], p[4 * g + 3]);
        }
        u32 X[8];
        #pragma unroll
        for (int i = 0; i < 8; ++i) X[i] = __shfl_xor(P[i], 32);
        union { u32 u[4]; short8 s; } c0, c1;
        c0.u[0] = h ? X[2] : P[0];  c0.u[1] = h ? X[3] : P[1];
        c0.u[2] = h ? P[2] : X[0];  c0.u[3] = h ? P[3] : X[1];
        c1.u[0] = h ? X[6] : P[4];  c1.u[1] = h ? X[7] : P[5];
        c1.u[2] = h ? P[6] : X[4];  c1.u[3] = h ? P[7] : X[5];
        #pragma unroll
        for (int r = 0; r < 16; ++r) O[r] *= fs;
        O = __builtin_amdgcn_mfma_f32_32x32x16_bf16(vf0, c0.s, O, 0, 0, 0);
        O = __builtin_amdgcn_mfma_f32_32x32x16_bf16(vf1, c1.s, O, 0, 0, 0);
    };

    for (int kt = 0; kt < 16; ++kt) {
        int k0 = kt * 32;
        int krow = k0 + ql;
        int ksw = (krow >> 1) & 3;
        short8 kf0 = *reinterpret_cast<const short8*>(Kbuf + krow * 32 + ((0 + h) ^ ksw) * 8);
        short8 kf1 = *reinterpret_cast<const short8*>(Kbuf + krow * 32 + ((2 + h) ^ ksw) * 8);
        int ko0 = k0 + h * 8;
        int ko1 = k0 + 16 + h * 8;
        short8 vf0 = *reinterpret_cast<const short8*>(Vt + ql * 512 + ((ko0 >> 3) ^ (ql & 7)) * 8);
        short8 vf1 = *reinterpret_cast<const short8*>(Vt + ql * 512 + ((ko1 >> 3) ^ (ql & 7)) * 8);
        process(0, O0, m0, su0, kf0, kf1, vf0, vf1);
        process(1, O1, m1, su1, kf0, kf1, vf0, vf1);
    }

    // epilogue: normalize + fused LePE from LDS, write bf16.
    // lane's O reg r -> channel d = (r&3) + 8*(r>>2) + 4h (within head)
    #pragma unroll
    for (int QS = 0; QS < 2; ++QS) {
        f32x16& O = QS ? O1 : O0;
        float inv = 1.f / (QS ? su1 : su0);
        int qrow = q0 + QS * 32 + ql;
        int hs  = (br == 0) ? (qrow >> 3) : (qrow >> 6);
        int wsx = (br == 0) ? (qrow & 7)  : (qrow & 63);

        float lep[16];
        #pragma unroll
        for (int r = 0; r < 16; ++r) {
            int d = (r & 3) + 8 * (r >> 2) + 4 * h;
            lep[r] = gbl[d];
        }
        #pragma unroll
        for (int dy = -1; dy <= 1; ++dy) {
            int hn = hs + dy;
            bool okh = (br == 0) ? ((unsigned)hn < 64u) : ((unsigned)hn < 8u);
            #pragma unroll
            for (int dx = -1; dx <= 1; ++dx) {
                int wn = wsx + dx;
                bool okw = (br == 0) ? ((unsigned)wn < 8u) : ((unsigned)wn < 64u);
                if (okh && okw) {
                    int key = (br == 0) ? (hn * 8 + wn) : (hn * 64 + wn);
                    int t = (dy + 1) * 3 + (dx + 1);
                    #pragma unroll
                    for (int r = 0; r < 16; ++r) {
                        int d = (r & 3) + 8 * (r >> 2) + 4 * h;
                        float vv = bf2f((u32)(unsigned short)
                            Vt[d * 512 + (((key >> 3) ^ (d & 7)) * 8 + (key & 7))]);
                        lep[r] += vv * gwl[d * 9 + t];
                    }
                }
            }
        }

        int l = (br == 0) ? ((qrow >> 3) * 64 + wi * 8 + (qrow & 7)) : (wi * 512 + qrow);
        unsigned short* orow = att + ((size_t)(bb * 4096 + l)) * 256 + qk_off;
        #pragma unroll
        for (int g = 0; g < 4; ++g) {
            u32 lo = pk2(O[4 * g] * inv + lep[4 * g],
                         O[4 * g + 1] * inv + lep[4 * g + 1]);
            u32 hi = pk2(O[4 * g + 2] * inv + lep[4 * g + 2],
                         O[4 * g + 3] * inv + lep[4 * g + 3]);
            *reinterpret_cast<uint2*>(orow + 8 * g + 4 * h) = make_uint2(lo, hi);
        }
    }
}

// ---------------------------------------------------------------------------
extern "C" void kernel_launch(void* const* d_in, const int* in_sizes, int n_in,
                              void* d_out, int out_size, void* d_ws, size_t ws_size,
                              hipStream_t stream) {
    const float* x     = (const float*)d_in[0];
    const float* n1w   = (const float*)d_in[1];
    const float* n1b   = (const float*)d_in[2];
    const float* qkvw  = (const float*)d_in[3];
    const float* gw0   = (const float*)d_in[4];
    const float* gb0   = (const float*)d_in[5];
    const float* gw1   = (const float*)d_in[6];
    const float* gb1   = (const float*)d_in[7];
    const float* projw = (const float*)d_in[8];
    const float* projb = (const float*)d_in[9];
    const float* n2w   = (const float*)d_in[10];
    const float* n2b   = (const float*)d_in[11];
    const float* fc1w  = (const float*)d_in[12];
    const float* fc1b  = (const float*)d_in[13];
    const float* fc2w  = (const float*)d_in[14];
    const float* fc2b  = (const float*)d_in[15];
    float* out = (float*)d_out;
    char* wsb  = (char*)d_ws;

    // workspace layout (bytes)
    float*          xT   = (float*)wsb;                          // 16,777,216
    unsigned short* qkv  = (unsigned short*)(wsb + 16777216);    // 16,777,216
    unsigned short* att  = (unsigned short*)(wsb + 33554432);    //  8,388,608
    unsigned short* img  = (unsigned short*)(wsb + 41943040);    //  8,388,608
    unsigned short* wq   = (unsigned short*)(wsb + 50331648);    //    262,144
    unsigned short* wp   = (unsigned short*)(wsb + 50593792);    //    131,072
    unsigned short* w1   = (unsigned short*)(wsb + 50724864);    //    524,288
    unsigned short* w2   = (unsigned short*)(wsb + 51249152);    //    524,288
    unsigned short* ynorm  = img;                                // reuse
    unsigned short* hidden = (unsigned short*)wsb;               // overlays xT+qkv (dead by fc1)

    // weight fp32 -> bf16 (one launch)
    cvt4_kernel<<<704, 256, 0, stream>>>(qkvw, projw, fc1w, fc2w, wq, wp, w1, w2);

    // norm1 (+ raw fp32 transpose for residual), bf16 out
    norm_kernel<<<4096, 256, 0, stream>>>(x, n1w, n1b, img, xT, 1);
    // qkv = img @ qkv_w^T -> bf16 (16384 x 512)
    mfma_gemm<<<dim3(8, 256), 256, 0, stream>>>(img, wq, nullptr, nullptr, qkv, 512, 256, 1);
    // MFMA windowed attention + fused LePE -> bf16 att
    attn_kernel<<<256, 512, 0, stream>>>(qkv, gw0, gb0, gw1, gb1, att);
    // out = xT + att @ proj_w^T + proj_b (fp32)
    mfma_gemm<<<dim3(4, 256), 256, 0, stream>>>(att, wp, projb, xT, out, 256, 256, 3);
    // norm2 -> bf16
    norm_kernel<<<4096, 256, 0, stream>>>(out, n2w, n2b, ynorm, nullptr, 0);
    // fc1: gelu -> bf16 hidden (16384 x 1024)
    mfma_gemm<<<dim3(16, 256), 256, 0, stream>>>(ynorm, w1, fc1b, nullptr, hidden, 1024, 256, 2);
    // fc2: + bias + resid(out) -> out (16384 x 256)
    mfma_gemm<<<dim3(4, 256), 256, 0, stream>>>(hidden, w2, fc2b, out, out, 256, 1024, 3);
}